// Round 12
// baseline (202.894 us; speedup 1.0000x reference)
//
#include <hip/hip_runtime.h>

#define NN 50000
#define NE 800000
#define C 64
#define NL 4
#define SCAN_NB 196        // ceil(50000/256)
#define PAD 16             // ints per node counter (64B line each)

// ---- bf16 helpers (RNE) ----
__device__ __forceinline__ unsigned short f2bf(float f) {
    unsigned u = __float_as_uint(f);
    u += 0x7fffu + ((u >> 16) & 1u);
    return (unsigned short)(u >> 16);
}
__device__ __forceinline__ float4 bf4_to_f4(uint2 p) {
    float4 r;
    r.x = __uint_as_float(p.x << 16);
    r.y = __uint_as_float(p.x & 0xffff0000u);
    r.z = __uint_as_float(p.y << 16);
    r.w = __uint_as_float(p.y & 0xffff0000u);
    return r;
}

// ---------------- init: zero padded counters (NN*PAD ints = 3.2MB) ----------------
__global__ void init_kernel(int4* __restrict__ p) {
    int i = blockIdx.x * blockDim.x + threadIdx.x;
    int stride = gridDim.x * blockDim.x;
    for (int j = i; j < NN * PAD / 4; j += stride)
        p[j] = make_int4(0, 0, 0, 0);
}

// ---------------- histogram + rank: each counter on its own 64B line ----------------
__global__ void hist_rank_kernel(const int* __restrict__ dst, int* __restrict__ deg_pad,
                                 int* __restrict__ rank) {
    int e = blockIdx.x * blockDim.x + threadIdx.x;
    if (e < NE) rank[e] = atomicAdd(&deg_pad[dst[e] * PAD], 1);
}

// ---------------- scan1: reads padded counters ----------------
__global__ __launch_bounds__(256) void scan1_kernel(const int* __restrict__ deg_pad,
                                                    int* __restrict__ row_start,
                                                    int* __restrict__ bsums) {
    __shared__ int sdata[256];
    int tid = threadIdx.x;
    int i = blockIdx.x * 256 + tid;
    int v = (i < NN) ? deg_pad[i * PAD] : 0;
    sdata[tid] = v;
    __syncthreads();
    for (int off = 1; off < 256; off <<= 1) {
        int t = (tid >= off) ? sdata[tid - off] : 0;
        __syncthreads();
        sdata[tid] += t;
        __syncthreads();
    }
    int incl = sdata[tid];
    if (i < NN) row_start[i] = incl - v;
    if (tid == 255) bsums[blockIdx.x] = incl;
}

// ---------------- scan23: apply block offsets + emit compact deg / deg_inv ----------------
__global__ __launch_bounds__(256) void scan23_kernel(int* __restrict__ row_start,
                                                     const int* __restrict__ bsums,
                                                     const int* __restrict__ deg_pad,
                                                     int* __restrict__ deg,
                                                     float* __restrict__ deg_inv) {
    __shared__ int sdata[256];
    int tid = threadIdx.x;
    int v = (tid < SCAN_NB) ? bsums[tid] : 0;
    sdata[tid] = v;
    __syncthreads();
    for (int off = 1; off < 256; off <<= 1) {
        int t = (tid >= off) ? sdata[tid - off] : 0;
        __syncthreads();
        sdata[tid] += t;
        __syncthreads();
    }
    int b = blockIdx.x;
    int offset = (b == 0) ? 0 : sdata[b - 1];
    int i = b * 256 + tid;
    if (i < NN) {
        row_start[i] += offset;
        int cnt = deg_pad[i * PAD];
        deg[i] = cnt;
        deg_inv[i] = 1.0f / fmaxf((float)cnt, 1.0f);
    }
}

// ---------------- CSR fill: no atomics, 4 edges/thread ----------------
__global__ void fill_kernel(const int* __restrict__ src, const int* __restrict__ dst,
                            const int* __restrict__ rank, const int* __restrict__ row_start,
                            int* __restrict__ csr_src) {
    int t = blockIdx.x * blockDim.x + threadIdx.x;
    int e0 = t * 4;
    if (e0 + 3 < NE) {
        int4 d4 = ((const int4*)dst)[t];
        int4 r4 = ((const int4*)rank)[t];
        int4 s4 = ((const int4*)src)[t];
        csr_src[row_start[d4.x] + r4.x] = s4.x;
        csr_src[row_start[d4.y] + r4.y] = s4.y;
        csr_src[row_start[d4.z] + r4.z] = s4.z;
        csr_src[row_start[d4.w] + r4.w] = s4.w;
    } else if (e0 < NE) {
        for (int e = e0; e < NE; e++)
            csr_src[row_start[dst[e]] + rank[e]] = src[e];
    }
}

// ---------------- layer-0 transform: y = x@Wl (bf16), z = x@Wr + b (fp32) ----------------
__global__ __launch_bounds__(512) void transform_kernel(
    const float* __restrict__ xin,
    const float* __restrict__ Wl, const float* __restrict__ Wr,
    const float* __restrict__ bias,
    unsigned short* __restrict__ y, float* __restrict__ z)
{
    __shared__ float wl[C * C];
    __shared__ float wr[C * C];
    __shared__ float xs[64][C + 4];

    int tid = threadIdx.x;
    for (int i = tid; i < C * C / 4; i += 512) {
        ((float4*)wl)[i] = ((const float4*)Wl)[i];
        ((float4*)wr)[i] = ((const float4*)Wr)[i];
    }
    int node0 = blockIdx.x * 64;
    for (int i = tid; i < 64 * 16; i += 512) {
        int nl = i >> 4;
        int c4 = i & 15;
        int n = node0 + nl;
        int nc = n < NN ? n : NN - 1;
        float4 v = ((const float4*)xin)[(size_t)nc * 16 + c4];
        *(float4*)&xs[nl][c4 * 4] = v;
    }
    __syncthreads();

    int c4 = tid & 15;
    int np = tid >> 4;
    float4 b4 = ((const float4*)bias)[c4];
    float4 y0 = make_float4(0.f, 0.f, 0.f, 0.f);
    float4 y1 = make_float4(0.f, 0.f, 0.f, 0.f);
    float4 z0 = b4;
    float4 z1 = b4;
    #pragma unroll 16
    for (int k = 0; k < C; k++) {
        float xv0 = xs[np][k];
        float xv1 = xs[np + 32][k];
        float4 wlv = *(const float4*)&wl[k * C + c4 * 4];
        float4 wrv = *(const float4*)&wr[k * C + c4 * 4];
        y0.x += xv0 * wlv.x; y0.y += xv0 * wlv.y; y0.z += xv0 * wlv.z; y0.w += xv0 * wlv.w;
        z0.x += xv0 * wrv.x; z0.y += xv0 * wrv.y; z0.z += xv0 * wrv.z; z0.w += xv0 * wrv.w;
        y1.x += xv1 * wlv.x; y1.y += xv1 * wlv.y; y1.z += xv1 * wlv.z; y1.w += xv1 * wlv.w;
        z1.x += xv1 * wrv.x; z1.y += xv1 * wrv.y; z1.z += xv1 * wrv.z; z1.w += xv1 * wrv.w;
    }
    int n0 = node0 + np;
    int n1 = node0 + np + 32;
    if (n0 < NN) {
        ushort4 p = make_ushort4(f2bf(y0.x), f2bf(y0.y), f2bf(y0.z), f2bf(y0.w));
        *(ushort4*)&y[(size_t)n0 * C + c4 * 4] = p;
        ((float4*)z)[(size_t)n0 * 16 + c4] = z0;
    }
    if (n1 < NN) {
        ushort4 p = make_ushort4(f2bf(y1.x), f2bf(y1.y), f2bf(y1.z), f2bf(y1.w));
        *(ushort4*)&y[(size_t)n1 * C + c4 * 4] = p;
        ((float4*)z)[(size_t)n1 * 16 + c4] = z1;
    }
}

// ---------------- gather core: bf16 rows, masked unroll-8 ----------------
__device__ __forceinline__ float4 gather_row(const uint2* __restrict__ yb,
                                             const int* __restrict__ cp, int d, int ql) {
    float4 acc = make_float4(0.f, 0.f, 0.f, 0.f);
    for (int t = 0; t < d; t += 8) {
        int lim = d - 1 - t;
        int j1 = min(1, lim), j2 = min(2, lim), j3 = min(3, lim);
        int j4 = min(4, lim), j5 = min(5, lim), j6 = min(6, lim), j7 = min(7, lim);
        float m1 = lim >= 1 ? 1.f : 0.f, m2 = lim >= 2 ? 1.f : 0.f;
        float m3 = lim >= 3 ? 1.f : 0.f, m4 = lim >= 4 ? 1.f : 0.f;
        float m5 = lim >= 5 ? 1.f : 0.f, m6 = lim >= 6 ? 1.f : 0.f;
        float m7 = lim >= 7 ? 1.f : 0.f;
        int s0 = cp[t];
        int s1 = cp[t + j1];
        int s2 = cp[t + j2];
        int s3 = cp[t + j3];
        int s4 = cp[t + j4];
        int s5 = cp[t + j5];
        int s6 = cp[t + j6];
        int s7 = cp[t + j7];
        uint2 p0 = yb[(size_t)s0 * 16 + ql];
        uint2 p1 = yb[(size_t)s1 * 16 + ql];
        uint2 p2 = yb[(size_t)s2 * 16 + ql];
        uint2 p3 = yb[(size_t)s3 * 16 + ql];
        uint2 p4 = yb[(size_t)s4 * 16 + ql];
        uint2 p5 = yb[(size_t)s5 * 16 + ql];
        uint2 p6 = yb[(size_t)s6 * 16 + ql];
        uint2 p7 = yb[(size_t)s7 * 16 + ql];
        float4 v0 = bf4_to_f4(p0);
        float4 v1 = bf4_to_f4(p1);
        float4 v2 = bf4_to_f4(p2);
        float4 v3 = bf4_to_f4(p3);
        float4 v4 = bf4_to_f4(p4);
        float4 v5 = bf4_to_f4(p5);
        float4 v6 = bf4_to_f4(p6);
        float4 v7 = bf4_to_f4(p7);
        acc.x += v0.x;      acc.y += v0.y;      acc.z += v0.z;      acc.w += v0.w;
        acc.x += v1.x * m1; acc.y += v1.y * m1; acc.z += v1.z * m1; acc.w += v1.w * m1;
        acc.x += v2.x * m2; acc.y += v2.y * m2; acc.z += v2.z * m2; acc.w += v2.w * m2;
        acc.x += v3.x * m3; acc.y += v3.y * m3; acc.z += v3.z * m3; acc.w += v3.w * m3;
        acc.x += v4.x * m4; acc.y += v4.y * m4; acc.z += v4.z * m4; acc.w += v4.w * m4;
        acc.x += v5.x * m5; acc.y += v5.y * m5; acc.z += v5.z * m5; acc.w += v5.w * m5;
        acc.x += v6.x * m6; acc.y += v6.y * m6; acc.z += v6.z * m6; acc.w += v6.w * m6;
        acc.x += v7.x * m7; acc.y += v7.y * m7; acc.z += v7.z * m7; acc.w += v7.w * m7;
    }
    return acc;
}

// ---------------- fused: gather layer l -> prelu -> LDS -> transform layer l+1 ----------------
__global__ __launch_bounds__(512) void fused_gt_kernel(
    const uint2* __restrict__ yb, const float4* __restrict__ z4,
    const int* __restrict__ row_start, const int* __restrict__ deg,
    const float* __restrict__ deg_inv, const float* __restrict__ alpha,
    const int* __restrict__ csr_src,
    const float* __restrict__ Wl2, const float* __restrict__ Wr2,
    const float* __restrict__ bias2,
    unsigned short* __restrict__ yout, float* __restrict__ zout)
{
    __shared__ float wl[C * C];
    __shared__ float wr[C * C];
    __shared__ float xs[32][C + 4];
    __shared__ float bs2[C];

    int tid = threadIdx.x;
    for (int i = tid; i < C * C / 4; i += 512) {
        ((float4*)wl)[i] = ((const float4*)Wl2)[i];
        ((float4*)wr)[i] = ((const float4*)Wr2)[i];
    }
    if (tid < C) bs2[tid] = bias2[tid];

    int nl = tid >> 4;        // 0..31
    int ql = tid & 15;
    int n = blockIdx.x * 32 + nl;

    float4 o = make_float4(0.f, 0.f, 0.f, 0.f);
    if (n < NN) {
        int rs = row_start[n];
        int d = deg[n];
        float4 acc = gather_row(yb, csr_src + rs, d, ql);
        float di = deg_inv[n];
        float4 zz = z4[(size_t)n * 16 + ql];
        float4 a4 = ((const float4*)alpha)[ql];
        o.x = di * acc.x + zz.x;
        o.y = di * acc.y + zz.y;
        o.z = di * acc.z + zz.z;
        o.w = di * acc.w + zz.w;
        o.x = o.x >= 0.f ? o.x : a4.x * o.x;
        o.y = o.y >= 0.f ? o.y : a4.y * o.y;
        o.z = o.z >= 0.f ? o.z : a4.z * o.z;
        o.w = o.w >= 0.f ? o.w : a4.w * o.w;
    }
    *(float4*)&xs[nl][ql * 4] = o;
    __syncthreads();

    float4 b4 = *(const float4*)&bs2[ql * 4];
    float4 yv = make_float4(0.f, 0.f, 0.f, 0.f);
    float4 zv = b4;
    #pragma unroll 16
    for (int k = 0; k < C; k++) {
        float xv = xs[nl][k];
        float4 wlv = *(const float4*)&wl[k * C + ql * 4];
        float4 wrv = *(const float4*)&wr[k * C + ql * 4];
        yv.x += xv * wlv.x; yv.y += xv * wlv.y; yv.z += xv * wlv.z; yv.w += xv * wlv.w;
        zv.x += xv * wrv.x; zv.y += xv * wrv.y; zv.z += xv * wrv.z; zv.w += xv * wrv.w;
    }
    if (n < NN) {
        ushort4 p = make_ushort4(f2bf(yv.x), f2bf(yv.y), f2bf(yv.z), f2bf(yv.w));
        *(ushort4*)&yout[(size_t)n * C + ql * 4] = p;
        ((float4*)zout)[(size_t)n * 16 + ql] = zv;
    }
}

// ---------------- final gather (layer 3): writes d_out fp32 ----------------
__global__ __launch_bounds__(256) void gather_kernel(
    const uint2* __restrict__ yb, const float4* __restrict__ z4,
    const int* __restrict__ row_start, const int* __restrict__ deg,
    const float* __restrict__ deg_inv, const float* __restrict__ alpha,
    const int* __restrict__ csr_src,
    float4* __restrict__ out4)
{
    int tid = threadIdx.x;
    int n = blockIdx.x * 16 + (tid >> 4);   // 3125*16 = 50000 exact
    int ql = tid & 15;

    int rs = row_start[n];
    int d = deg[n];
    float4 acc = gather_row(yb, csr_src + rs, d, ql);

    float di = deg_inv[n];
    float4 zz = z4[(size_t)n * 16 + ql];
    float4 a4 = ((const float4*)alpha)[ql];
    float4 o;
    o.x = di * acc.x + zz.x;
    o.y = di * acc.y + zz.y;
    o.z = di * acc.z + zz.z;
    o.w = di * acc.w + zz.w;
    o.x = o.x >= 0.f ? o.x : a4.x * o.x;
    o.y = o.y >= 0.f ? o.y : a4.y * o.y;
    o.z = o.z >= 0.f ? o.z : a4.z * o.z;
    o.w = o.w >= 0.f ? o.w : a4.w * o.w;
    out4[(size_t)n * 16 + ql] = o;
}

extern "C" void kernel_launch(void* const* d_in, const int* in_sizes, int n_in,
                              void* d_out, int out_size, void* d_ws, size_t ws_size,
                              hipStream_t stream) {
    const float* x     = (const float*)d_in[0];
    const int*   ei    = (const int*)d_in[1];
    const float* Wl    = (const float*)d_in[2];
    const float* Wr    = (const float*)d_in[3];
    const float* b     = (const float*)d_in[4];
    const float* alpha = (const float*)d_in[5];
    float* out = (float*)d_out;

    const int* src = ei;        // edge_index[0]
    const int* dst = ei + NE;   // edge_index[1]

    // workspace layout (all blocks 16B-aligned)
    char* wsp = (char*)d_ws;
    int*   deg_pad   = (int*)wsp;                   wsp += (size_t)NN * PAD * 4;   // 3.2MB
    int*   deg       = (int*)wsp;                   wsp += (size_t)NN * 4;
    float* deg_inv   = (float*)wsp;                 wsp += (size_t)NN * 4;
    int*   row_start = (int*)wsp;                   wsp += (size_t)NN * 4;
    int*   bsums     = (int*)wsp;                   wsp += 1024;
    int*   rankb     = (int*)wsp;                   wsp += (size_t)NE * 4;
    int*   csr_src   = (int*)wsp;                   wsp += (size_t)NE * 4;
    unsigned short* y0buf = (unsigned short*)wsp;   wsp += (size_t)NN * C * 2;
    unsigned short* y1buf = (unsigned short*)wsp;   wsp += (size_t)NN * C * 2;
    float* z0buf     = (float*)wsp;                 wsp += (size_t)NN * C * 4;
    float* z1buf     = (float*)wsp;

    // ---- CSR build ----
    init_kernel<<<800, 256, 0, stream>>>((int4*)deg_pad);
    hist_rank_kernel<<<(NE + 255) / 256, 256, 0, stream>>>(dst, deg_pad, rankb);
    scan1_kernel<<<SCAN_NB, 256, 0, stream>>>(deg_pad, row_start, bsums);
    scan23_kernel<<<SCAN_NB, 256, 0, stream>>>(row_start, bsums, deg_pad, deg, deg_inv);
    fill_kernel<<<(NE / 4 + 255) / 256, 256, 0, stream>>>(src, dst, rankb, row_start, csr_src);

    // ---- layer-0 transform ----
    transform_kernel<<<(NN + 63) / 64, 512, 0, stream>>>(x, Wl, Wr, b, y0buf, z0buf);

    // ---- fused (gather_l + transform_{l+1}) for l = 0,1,2; ping-pong ----
    const int fblocks = (NN + 31) / 32;
    unsigned short* ycur = y0buf; float* zcur = z0buf;
    unsigned short* ynxt = y1buf; float* znxt = z1buf;
    for (int l = 0; l < NL - 1; l++) {
        fused_gt_kernel<<<fblocks, 512, 0, stream>>>(
            (const uint2*)ycur, (const float4*)zcur,
            row_start, deg, deg_inv, alpha + (size_t)l * C, csr_src,
            Wl + (size_t)(l + 1) * C * C, Wr + (size_t)(l + 1) * C * C,
            b + (size_t)(l + 1) * C,
            ynxt, znxt);
        unsigned short* ty = ycur; float* tz = zcur;
        ycur = ynxt; zcur = znxt;
        ynxt = ty;   znxt = tz;
    }

    // ---- final gather (layer 3) -> d_out ----
    gather_kernel<<<NN / 16, 256, 0, stream>>>(
        (const uint2*)ycur, (const float4*)zcur, row_start, deg,
        deg_inv, alpha + (size_t)(NL - 1) * C, csr_src, (float4*)out);
}

// Round 13
// 186.279 us; speedup vs baseline: 1.0892x; 1.0892x over previous
//
#include <hip/hip_runtime.h>

#define NN 50000
#define NE 800000
#define C 64
#define NL 4
#define SCAN_NB 196        // ceil(50000/256)

typedef __attribute__((ext_vector_type(8))) short bf16x8;
typedef __attribute__((ext_vector_type(4))) float f32x4;

// ---- bf16 helpers (RNE) ----
__device__ __forceinline__ unsigned short f2bf(float f) {
    unsigned u = __float_as_uint(f);
    u += 0x7fffu + ((u >> 16) & 1u);
    return (unsigned short)(u >> 16);
}
__device__ __forceinline__ float4 bf4_to_f4(uint2 p) {
    float4 r;
    r.x = __uint_as_float(p.x << 16);
    r.y = __uint_as_float(p.x & 0xffff0000u);
    r.z = __uint_as_float(p.y << 16);
    r.w = __uint_as_float(p.y & 0xffff0000u);
    return r;
}

// ---------------- init: zero deg_cnt ----------------
__global__ void init_kernel(int4* __restrict__ p) {
    int i = blockIdx.x * blockDim.x + threadIdx.x;
    if (i < (NN + 16) / 4) p[i] = make_int4(0, 0, 0, 0);
}

// ---------------- degree histogram + per-edge rank: 1 edge/thread ----------------
__global__ void hist_rank_kernel(const int* __restrict__ dst, int* __restrict__ deg_cnt,
                                 int* __restrict__ rank) {
    int e = blockIdx.x * blockDim.x + threadIdx.x;
    if (e < NE) rank[e] = atomicAdd(&deg_cnt[dst[e]], 1);
}

// ---------------- scan1 ----------------
__global__ __launch_bounds__(256) void scan1_kernel(const int* __restrict__ deg_cnt,
                                                    int* __restrict__ row_start,
                                                    int* __restrict__ bsums) {
    __shared__ int sdata[256];
    int tid = threadIdx.x;
    int i = blockIdx.x * 256 + tid;
    int v = (i < NN) ? deg_cnt[i] : 0;
    sdata[tid] = v;
    __syncthreads();
    for (int off = 1; off < 256; off <<= 1) {
        int t = (tid >= off) ? sdata[tid - off] : 0;
        __syncthreads();
        sdata[tid] += t;
        __syncthreads();
    }
    int incl = sdata[tid];
    if (i < NN) row_start[i] = incl - v;
    if (tid == 255) bsums[blockIdx.x] = incl;
}

// ---------------- scan23 ----------------
__global__ __launch_bounds__(256) void scan23_kernel(int* __restrict__ row_start,
                                                     const int* __restrict__ bsums,
                                                     const int* __restrict__ deg_cnt,
                                                     float* __restrict__ deg_inv) {
    __shared__ int sdata[256];
    int tid = threadIdx.x;
    int v = (tid < SCAN_NB) ? bsums[tid] : 0;
    sdata[tid] = v;
    __syncthreads();
    for (int off = 1; off < 256; off <<= 1) {
        int t = (tid >= off) ? sdata[tid - off] : 0;
        __syncthreads();
        sdata[tid] += t;
        __syncthreads();
    }
    int b = blockIdx.x;
    int offset = (b == 0) ? 0 : sdata[b - 1];
    int i = b * 256 + tid;
    if (i < NN) {
        row_start[i] += offset;
        deg_inv[i] = 1.0f / fmaxf((float)deg_cnt[i], 1.0f);
    }
}

// ---------------- CSR fill: no atomics, 4 edges/thread ----------------
__global__ void fill_kernel(const int* __restrict__ src, const int* __restrict__ dst,
                            const int* __restrict__ rank, const int* __restrict__ row_start,
                            int* __restrict__ csr_src) {
    int t = blockIdx.x * blockDim.x + threadIdx.x;
    int e0 = t * 4;
    if (e0 + 3 < NE) {
        int4 d4 = ((const int4*)dst)[t];
        int4 r4 = ((const int4*)rank)[t];
        int4 s4 = ((const int4*)src)[t];
        csr_src[row_start[d4.x] + r4.x] = s4.x;
        csr_src[row_start[d4.y] + r4.y] = s4.y;
        csr_src[row_start[d4.z] + r4.z] = s4.z;
        csr_src[row_start[d4.w] + r4.w] = s4.w;
    } else if (e0 < NE) {
        for (int e = e0; e < NE; e++)
            csr_src[row_start[dst[e]] + rank[e]] = src[e];
    }
}

// ---------------- layer-0 transform via MFMA: y = x@Wl (bf16), z = x@Wr + b ----------------
// 64 nodes/block, 512 threads = 8 waves. Wave w: M-tile mt = w>>1, half = w&1 (0:y/Wl, 1:z/Wr).
// Per wave: 4 N-tiles x 2 K-steps of mfma_f32_16x16x32_bf16.
// A frag assumption: lane l -> row = l&15, k = (l>>4)*8 + j (same convention for B;
// any common k-permutation cancels in A*B).
__global__ __launch_bounds__(512) void transform_mfma_kernel(
    const float* __restrict__ xin,
    const float* __restrict__ Wl, const float* __restrict__ Wr,
    const float* __restrict__ bias,
    unsigned short* __restrict__ y, float* __restrict__ z)
{
    __shared__ unsigned short xs[64][72];    // x bf16, row stride 144B (bank-spread)
    __shared__ unsigned short wlT[64][72];   // Wl^T bf16: [c][k]
    __shared__ unsigned short wrT[64][72];   // Wr^T bf16
    __shared__ unsigned short ys[64][64];    // y staging
    __shared__ float zs[64][64];             // z staging
    __shared__ float bs[C];

    int tid = threadIdx.x;
    int node0 = blockIdx.x * 64;

    // stage weights transposed + bf16
    for (int i = tid; i < C * C; i += 512) {
        int k = i >> 6, c = i & 63;
        wlT[c][k] = f2bf(Wl[i]);
        wrT[c][k] = f2bf(Wr[i]);
    }
    if (tid < C) bs[tid] = bias[tid];
    // stage x bf16
    for (int i = tid; i < 64 * 16; i += 512) {
        int nl = i >> 4, c4 = i & 15;
        int n = node0 + nl;
        int nc = n < NN ? n : NN - 1;
        float4 v = ((const float4*)xin)[(size_t)nc * 16 + c4];
        xs[nl][c4 * 4 + 0] = f2bf(v.x);
        xs[nl][c4 * 4 + 1] = f2bf(v.y);
        xs[nl][c4 * 4 + 2] = f2bf(v.z);
        xs[nl][c4 * 4 + 3] = f2bf(v.w);
    }
    __syncthreads();

    int w = tid >> 6;
    int l = tid & 63;
    int mt = w >> 1;          // 0..3
    int half = w & 1;         // 0: y, 1: z
    int r16 = l & 15;
    int kg = l >> 4;          // 0..3

    bf16x8 a0 = *(const bf16x8*)&xs[mt * 16 + r16][kg * 8];
    bf16x8 a1 = *(const bf16x8*)&xs[mt * 16 + r16][32 + kg * 8];

    f32x4 acc[4];
    #pragma unroll
    for (int nt = 0; nt < 4; nt++) {
        float bv = half ? bs[nt * 16 + r16] : 0.f;
        acc[nt] = (f32x4){bv, bv, bv, bv};
    }
    #pragma unroll
    for (int nt = 0; nt < 4; nt++) {
        const unsigned short* col = half ? &wrT[nt * 16 + r16][0] : &wlT[nt * 16 + r16][0];
        bf16x8 b0 = *(const bf16x8*)&col[kg * 8];
        bf16x8 b1 = *(const bf16x8*)&col[32 + kg * 8];
        acc[nt] = __builtin_amdgcn_mfma_f32_16x16x32_bf16(a0, b0, acc[nt], 0, 0, 0);
        acc[nt] = __builtin_amdgcn_mfma_f32_16x16x32_bf16(a1, b1, acc[nt], 0, 0, 0);
    }
    // C/D layout (verified): col = lane&15, row = (lane>>4)*4 + reg
    #pragma unroll
    for (int nt = 0; nt < 4; nt++) {
        #pragma unroll
        for (int j = 0; j < 4; j++) {
            int r = mt * 16 + kg * 4 + j;
            int c = nt * 16 + r16;
            if (half) zs[r][c] = acc[nt][j];
            else      ys[r][c] = f2bf(acc[nt][j]);
        }
    }
    __syncthreads();

    // coalesced store-out
    for (int i = tid; i < 64 * 16; i += 512) {
        int r = i >> 4, g = i & 15;
        int n = node0 + r;
        if (n < NN) {
            ((ushort4*)&y[(size_t)n * C])[g] = ((const ushort4*)&ys[r][0])[g];
            ((float4*)&z[(size_t)n * C])[g] = ((const float4*)&zs[r][0])[g];
        }
    }
}

// ---------------- gather core: bf16 rows, masked unroll-8 ----------------
__device__ __forceinline__ float4 gather_row(const uint2* __restrict__ yb,
                                             const int* __restrict__ cp, int d, int ql) {
    float4 acc = make_float4(0.f, 0.f, 0.f, 0.f);
    for (int t = 0; t < d; t += 8) {
        int lim = d - 1 - t;
        int j1 = min(1, lim), j2 = min(2, lim), j3 = min(3, lim);
        int j4 = min(4, lim), j5 = min(5, lim), j6 = min(6, lim), j7 = min(7, lim);
        float m1 = lim >= 1 ? 1.f : 0.f, m2 = lim >= 2 ? 1.f : 0.f;
        float m3 = lim >= 3 ? 1.f : 0.f, m4 = lim >= 4 ? 1.f : 0.f;
        float m5 = lim >= 5 ? 1.f : 0.f, m6 = lim >= 6 ? 1.f : 0.f;
        float m7 = lim >= 7 ? 1.f : 0.f;
        int s0 = cp[t];
        int s1 = cp[t + j1];
        int s2 = cp[t + j2];
        int s3 = cp[t + j3];
        int s4 = cp[t + j4];
        int s5 = cp[t + j5];
        int s6 = cp[t + j6];
        int s7 = cp[t + j7];
        uint2 p0 = yb[(size_t)s0 * 16 + ql];
        uint2 p1 = yb[(size_t)s1 * 16 + ql];
        uint2 p2 = yb[(size_t)s2 * 16 + ql];
        uint2 p3 = yb[(size_t)s3 * 16 + ql];
        uint2 p4 = yb[(size_t)s4 * 16 + ql];
        uint2 p5 = yb[(size_t)s5 * 16 + ql];
        uint2 p6 = yb[(size_t)s6 * 16 + ql];
        uint2 p7 = yb[(size_t)s7 * 16 + ql];
        float4 v0 = bf4_to_f4(p0);
        float4 v1 = bf4_to_f4(p1);
        float4 v2 = bf4_to_f4(p2);
        float4 v3 = bf4_to_f4(p3);
        float4 v4 = bf4_to_f4(p4);
        float4 v5 = bf4_to_f4(p5);
        float4 v6 = bf4_to_f4(p6);
        float4 v7 = bf4_to_f4(p7);
        acc.x += v0.x;      acc.y += v0.y;      acc.z += v0.z;      acc.w += v0.w;
        acc.x += v1.x * m1; acc.y += v1.y * m1; acc.z += v1.z * m1; acc.w += v1.w * m1;
        acc.x += v2.x * m2; acc.y += v2.y * m2; acc.z += v2.z * m2; acc.w += v2.w * m2;
        acc.x += v3.x * m3; acc.y += v3.y * m3; acc.z += v3.z * m3; acc.w += v3.w * m3;
        acc.x += v4.x * m4; acc.y += v4.y * m4; acc.z += v4.z * m4; acc.w += v4.w * m4;
        acc.x += v5.x * m5; acc.y += v5.y * m5; acc.z += v5.z * m5; acc.w += v5.w * m5;
        acc.x += v6.x * m6; acc.y += v6.y * m6; acc.z += v6.z * m6; acc.w += v6.w * m6;
        acc.x += v7.x * m7; acc.y += v7.y * m7; acc.z += v7.z * m7; acc.w += v7.w * m7;
    }
    return acc;
}

// ---------------- fused: gather layer l -> prelu -> LDS -> transform layer l+1 ----------------
__global__ __launch_bounds__(512) void fused_gt_kernel(
    const uint2* __restrict__ yb, const float4* __restrict__ z4,
    const int* __restrict__ row_start, const int* __restrict__ deg_cnt,
    const float* __restrict__ deg_inv, const float* __restrict__ alpha,
    const int* __restrict__ csr_src,
    const float* __restrict__ Wl2, const float* __restrict__ Wr2,
    const float* __restrict__ bias2,
    unsigned short* __restrict__ yout, float* __restrict__ zout)
{
    __shared__ float wl[C * C];
    __shared__ float wr[C * C];
    __shared__ float xs[32][C + 4];
    __shared__ float bs2[C];

    int tid = threadIdx.x;
    for (int i = tid; i < C * C / 4; i += 512) {
        ((float4*)wl)[i] = ((const float4*)Wl2)[i];
        ((float4*)wr)[i] = ((const float4*)Wr2)[i];
    }
    if (tid < C) bs2[tid] = bias2[tid];

    int nl = tid >> 4;        // 0..31
    int ql = tid & 15;
    int n = blockIdx.x * 32 + nl;

    float4 o = make_float4(0.f, 0.f, 0.f, 0.f);
    if (n < NN) {
        int rs = row_start[n];
        int d = deg_cnt[n];
        float4 acc = gather_row(yb, csr_src + rs, d, ql);
        float di = deg_inv[n];
        float4 zz = z4[(size_t)n * 16 + ql];
        float4 a4 = ((const float4*)alpha)[ql];
        o.x = di * acc.x + zz.x;
        o.y = di * acc.y + zz.y;
        o.z = di * acc.z + zz.z;
        o.w = di * acc.w + zz.w;
        o.x = o.x >= 0.f ? o.x : a4.x * o.x;
        o.y = o.y >= 0.f ? o.y : a4.y * o.y;
        o.z = o.z >= 0.f ? o.z : a4.z * o.z;
        o.w = o.w >= 0.f ? o.w : a4.w * o.w;
    }
    *(float4*)&xs[nl][ql * 4] = o;
    __syncthreads();

    float4 b4 = *(const float4*)&bs2[ql * 4];
    float4 yv = make_float4(0.f, 0.f, 0.f, 0.f);
    float4 zv = b4;
    #pragma unroll 16
    for (int k = 0; k < C; k++) {
        float xv = xs[nl][k];
        float4 wlv = *(const float4*)&wl[k * C + ql * 4];
        float4 wrv = *(const float4*)&wr[k * C + ql * 4];
        yv.x += xv * wlv.x; yv.y += xv * wlv.y; yv.z += xv * wlv.z; yv.w += xv * wlv.w;
        zv.x += xv * wrv.x; zv.y += xv * wrv.y; zv.z += xv * wrv.z; zv.w += xv * wrv.w;
    }
    if (n < NN) {
        ushort4 p = make_ushort4(f2bf(yv.x), f2bf(yv.y), f2bf(yv.z), f2bf(yv.w));
        *(ushort4*)&yout[(size_t)n * C + ql * 4] = p;
        ((float4*)zout)[(size_t)n * 16 + ql] = zv;
    }
}

// ---------------- final gather (layer 3): writes d_out fp32 ----------------
__global__ __launch_bounds__(256) void gather_kernel(
    const uint2* __restrict__ yb, const float4* __restrict__ z4,
    const int* __restrict__ row_start, const int* __restrict__ deg_cnt,
    const float* __restrict__ deg_inv, const float* __restrict__ alpha,
    const int* __restrict__ csr_src,
    float4* __restrict__ out4)
{
    int tid = threadIdx.x;
    int n = blockIdx.x * 16 + (tid >> 4);   // 3125*16 = 50000 exact
    int ql = tid & 15;

    int rs = row_start[n];
    int d = deg_cnt[n];
    float4 acc = gather_row(yb, csr_src + rs, d, ql);

    float di = deg_inv[n];
    float4 zz = z4[(size_t)n * 16 + ql];
    float4 a4 = ((const float4*)alpha)[ql];
    float4 o;
    o.x = di * acc.x + zz.x;
    o.y = di * acc.y + zz.y;
    o.z = di * acc.z + zz.z;
    o.w = di * acc.w + zz.w;
    o.x = o.x >= 0.f ? o.x : a4.x * o.x;
    o.y = o.y >= 0.f ? o.y : a4.y * o.y;
    o.z = o.z >= 0.f ? o.z : a4.z * o.z;
    o.w = o.w >= 0.f ? o.w : a4.w * o.w;
    out4[(size_t)n * 16 + ql] = o;
}

extern "C" void kernel_launch(void* const* d_in, const int* in_sizes, int n_in,
                              void* d_out, int out_size, void* d_ws, size_t ws_size,
                              hipStream_t stream) {
    const float* x     = (const float*)d_in[0];
    const int*   ei    = (const int*)d_in[1];
    const float* Wl    = (const float*)d_in[2];
    const float* Wr    = (const float*)d_in[3];
    const float* b     = (const float*)d_in[4];
    const float* alpha = (const float*)d_in[5];
    float* out = (float*)d_out;

    const int* src = ei;        // edge_index[0]
    const int* dst = ei + NE;   // edge_index[1]

    // workspace layout (all blocks 16B-aligned)
    char* wsp = (char*)d_ws;
    int*   deg_cnt   = (int*)wsp;                   wsp += (size_t)(NN + 16) * 4;
    float* deg_inv   = (float*)wsp;                 wsp += (size_t)NN * 4;
    int*   row_start = (int*)wsp;                   wsp += (size_t)NN * 4;
    int*   bsums     = (int*)wsp;                   wsp += 1024;
    int*   rankb     = (int*)wsp;                   wsp += (size_t)NE * 4;
    int*   csr_src   = (int*)wsp;                   wsp += (size_t)NE * 4;
    unsigned short* y0buf = (unsigned short*)wsp;   wsp += (size_t)NN * C * 2;
    unsigned short* y1buf = (unsigned short*)wsp;   wsp += (size_t)NN * C * 2;
    float* z0buf     = (float*)wsp;                 wsp += (size_t)NN * C * 4;
    float* z1buf     = (float*)wsp;

    // ---- CSR build ----
    init_kernel<<<49, 256, 0, stream>>>((int4*)deg_cnt);
    hist_rank_kernel<<<(NE + 255) / 256, 256, 0, stream>>>(dst, deg_cnt, rankb);
    scan1_kernel<<<SCAN_NB, 256, 0, stream>>>(deg_cnt, row_start, bsums);
    scan23_kernel<<<SCAN_NB, 256, 0, stream>>>(row_start, bsums, deg_cnt, deg_inv);
    fill_kernel<<<(NE / 4 + 255) / 256, 256, 0, stream>>>(src, dst, rankb, row_start, csr_src);

    // ---- layer-0 transform (MFMA probe) ----
    transform_mfma_kernel<<<(NN + 63) / 64, 512, 0, stream>>>(x, Wl, Wr, b, y0buf, z0buf);

    // ---- fused (gather_l + transform_{l+1}) for l = 0,1,2; ping-pong ----
    const int fblocks = (NN + 31) / 32;
    unsigned short* ycur = y0buf; float* zcur = z0buf;
    unsigned short* ynxt = y1buf; float* znxt = z1buf;
    for (int l = 0; l < NL - 1; l++) {
        fused_gt_kernel<<<fblocks, 512, 0, stream>>>(
            (const uint2*)ycur, (const float4*)zcur,
            row_start, deg_cnt, deg_inv, alpha + (size_t)l * C, csr_src,
            Wl + (size_t)(l + 1) * C * C, Wr + (size_t)(l + 1) * C * C,
            b + (size_t)(l + 1) * C,
            ynxt, znxt);
        unsigned short* ty = ycur; float* tz = zcur;
        ycur = ynxt; zcur = znxt;
        ynxt = ty;   znxt = tz;
    }

    // ---- final gather (layer 3) -> d_out ----
    gather_kernel<<<NN / 16, 256, 0, stream>>>(
        (const uint2*)ycur, (const float4*)zcur, row_start, deg_cnt,
        deg_inv, alpha + (size_t)(NL - 1) * C, csr_src, (float4*)out);
}

// Round 14
// 172.210 us; speedup vs baseline: 1.1782x; 1.0817x over previous
//
#include <hip/hip_runtime.h>

#define NN 50000
#define NE 800000
#define C 64
#define NL 4
#define SCAN_NB 196        // ceil(50000/256)

typedef __attribute__((ext_vector_type(8))) short bf16x8;
typedef __attribute__((ext_vector_type(4))) float f32x4;

// ---- bf16 helpers (RNE) ----
__device__ __forceinline__ unsigned short f2bf(float f) {
    unsigned u = __float_as_uint(f);
    u += 0x7fffu + ((u >> 16) & 1u);
    return (unsigned short)(u >> 16);
}
__device__ __forceinline__ float4 bf4_to_f4(uint2 p) {
    float4 r;
    r.x = __uint_as_float(p.x << 16);
    r.y = __uint_as_float(p.x & 0xffff0000u);
    r.z = __uint_as_float(p.y << 16);
    r.w = __uint_as_float(p.y & 0xffff0000u);
    return r;
}

// ---------------- init: zero deg_cnt ----------------
__global__ void init_kernel(int4* __restrict__ p) {
    int i = blockIdx.x * blockDim.x + threadIdx.x;
    if (i < (NN + 16) / 4) p[i] = make_int4(0, 0, 0, 0);
}

// ---------------- degree histogram + per-edge rank: 1 edge/thread ----------------
__global__ void hist_rank_kernel(const int* __restrict__ dst, int* __restrict__ deg_cnt,
                                 int* __restrict__ rank) {
    int e = blockIdx.x * blockDim.x + threadIdx.x;
    if (e < NE) rank[e] = atomicAdd(&deg_cnt[dst[e]], 1);
}

// ---------------- scan1 ----------------
__global__ __launch_bounds__(256) void scan1_kernel(const int* __restrict__ deg_cnt,
                                                    int* __restrict__ row_start,
                                                    int* __restrict__ bsums) {
    __shared__ int sdata[256];
    int tid = threadIdx.x;
    int i = blockIdx.x * 256 + tid;
    int v = (i < NN) ? deg_cnt[i] : 0;
    sdata[tid] = v;
    __syncthreads();
    for (int off = 1; off < 256; off <<= 1) {
        int t = (tid >= off) ? sdata[tid - off] : 0;
        __syncthreads();
        sdata[tid] += t;
        __syncthreads();
    }
    int incl = sdata[tid];
    if (i < NN) row_start[i] = incl - v;
    if (tid == 255) bsums[blockIdx.x] = incl;
}

// ---------------- scan23 ----------------
__global__ __launch_bounds__(256) void scan23_kernel(int* __restrict__ row_start,
                                                     const int* __restrict__ bsums,
                                                     const int* __restrict__ deg_cnt,
                                                     float* __restrict__ deg_inv) {
    __shared__ int sdata[256];
    int tid = threadIdx.x;
    int v = (tid < SCAN_NB) ? bsums[tid] : 0;
    sdata[tid] = v;
    __syncthreads();
    for (int off = 1; off < 256; off <<= 1) {
        int t = (tid >= off) ? sdata[tid - off] : 0;
        __syncthreads();
        sdata[tid] += t;
        __syncthreads();
    }
    int b = blockIdx.x;
    int offset = (b == 0) ? 0 : sdata[b - 1];
    int i = b * 256 + tid;
    if (i < NN) {
        row_start[i] += offset;
        deg_inv[i] = 1.0f / fmaxf((float)deg_cnt[i], 1.0f);
    }
}

// ---------------- CSR fill: no atomics, 4 edges/thread ----------------
__global__ void fill_kernel(const int* __restrict__ src, const int* __restrict__ dst,
                            const int* __restrict__ rank, const int* __restrict__ row_start,
                            int* __restrict__ csr_src) {
    int t = blockIdx.x * blockDim.x + threadIdx.x;
    int e0 = t * 4;
    if (e0 + 3 < NE) {
        int4 d4 = ((const int4*)dst)[t];
        int4 r4 = ((const int4*)rank)[t];
        int4 s4 = ((const int4*)src)[t];
        csr_src[row_start[d4.x] + r4.x] = s4.x;
        csr_src[row_start[d4.y] + r4.y] = s4.y;
        csr_src[row_start[d4.z] + r4.z] = s4.z;
        csr_src[row_start[d4.w] + r4.w] = s4.w;
    } else if (e0 < NE) {
        for (int e = e0; e < NE; e++)
            csr_src[row_start[dst[e]] + rank[e]] = src[e];
    }
}

// ---------------- layer-0 transform via MFMA (validated R13) ----------------
__global__ __launch_bounds__(512) void transform_mfma_kernel(
    const float* __restrict__ xin,
    const float* __restrict__ Wl, const float* __restrict__ Wr,
    const float* __restrict__ bias,
    unsigned short* __restrict__ y, float* __restrict__ z)
{
    __shared__ unsigned short xs[64][72];
    __shared__ unsigned short wlT[64][72];
    __shared__ unsigned short wrT[64][72];
    __shared__ unsigned short ys[64][64];
    __shared__ float zs[64][64];
    __shared__ float bs[C];

    int tid = threadIdx.x;
    int node0 = blockIdx.x * 64;

    for (int i = tid; i < C * C; i += 512) {
        int k = i >> 6, c = i & 63;
        wlT[c][k] = f2bf(Wl[i]);
        wrT[c][k] = f2bf(Wr[i]);
    }
    if (tid < C) bs[tid] = bias[tid];
    for (int i = tid; i < 64 * 16; i += 512) {
        int nl = i >> 4, c4 = i & 15;
        int n = node0 + nl;
        int nc = n < NN ? n : NN - 1;
        float4 v = ((const float4*)xin)[(size_t)nc * 16 + c4];
        xs[nl][c4 * 4 + 0] = f2bf(v.x);
        xs[nl][c4 * 4 + 1] = f2bf(v.y);
        xs[nl][c4 * 4 + 2] = f2bf(v.z);
        xs[nl][c4 * 4 + 3] = f2bf(v.w);
    }
    __syncthreads();

    int w = tid >> 6;
    int l = tid & 63;
    int mt = w >> 1;
    int half = w & 1;
    int r16 = l & 15;
    int kg = l >> 4;

    bf16x8 a0 = *(const bf16x8*)&xs[mt * 16 + r16][kg * 8];
    bf16x8 a1 = *(const bf16x8*)&xs[mt * 16 + r16][32 + kg * 8];

    f32x4 acc[4];
    #pragma unroll
    for (int nt = 0; nt < 4; nt++) {
        float bv = half ? bs[nt * 16 + r16] : 0.f;
        acc[nt] = (f32x4){bv, bv, bv, bv};
    }
    #pragma unroll
    for (int nt = 0; nt < 4; nt++) {
        const unsigned short* col = half ? &wrT[nt * 16 + r16][0] : &wlT[nt * 16 + r16][0];
        bf16x8 b0 = *(const bf16x8*)&col[kg * 8];
        bf16x8 b1 = *(const bf16x8*)&col[32 + kg * 8];
        acc[nt] = __builtin_amdgcn_mfma_f32_16x16x32_bf16(a0, b0, acc[nt], 0, 0, 0);
        acc[nt] = __builtin_amdgcn_mfma_f32_16x16x32_bf16(a1, b1, acc[nt], 0, 0, 0);
    }
    #pragma unroll
    for (int nt = 0; nt < 4; nt++) {
        #pragma unroll
        for (int j = 0; j < 4; j++) {
            int r = mt * 16 + kg * 4 + j;
            int c = nt * 16 + r16;
            if (half) zs[r][c] = acc[nt][j];
            else      ys[r][c] = f2bf(acc[nt][j]);
        }
    }
    __syncthreads();

    for (int i = tid; i < 64 * 16; i += 512) {
        int r = i >> 4, g = i & 15;
        int n = node0 + r;
        if (n < NN) {
            ((ushort4*)&y[(size_t)n * C])[g] = ((const ushort4*)&ys[r][0])[g];
            ((float4*)&z[(size_t)n * C])[g] = ((const float4*)&zs[r][0])[g];
        }
    }
}

// ---------------- gather core: bf16 rows, masked unroll-8 ----------------
__device__ __forceinline__ float4 gather_row(const uint2* __restrict__ yb,
                                             const int* __restrict__ cp, int d, int ql) {
    float4 acc = make_float4(0.f, 0.f, 0.f, 0.f);
    for (int t = 0; t < d; t += 8) {
        int lim = d - 1 - t;
        int j1 = min(1, lim), j2 = min(2, lim), j3 = min(3, lim);
        int j4 = min(4, lim), j5 = min(5, lim), j6 = min(6, lim), j7 = min(7, lim);
        float m1 = lim >= 1 ? 1.f : 0.f, m2 = lim >= 2 ? 1.f : 0.f;
        float m3 = lim >= 3 ? 1.f : 0.f, m4 = lim >= 4 ? 1.f : 0.f;
        float m5 = lim >= 5 ? 1.f : 0.f, m6 = lim >= 6 ? 1.f : 0.f;
        float m7 = lim >= 7 ? 1.f : 0.f;
        int s0 = cp[t];
        int s1 = cp[t + j1];
        int s2 = cp[t + j2];
        int s3 = cp[t + j3];
        int s4 = cp[t + j4];
        int s5 = cp[t + j5];
        int s6 = cp[t + j6];
        int s7 = cp[t + j7];
        uint2 p0 = yb[(size_t)s0 * 16 + ql];
        uint2 p1 = yb[(size_t)s1 * 16 + ql];
        uint2 p2 = yb[(size_t)s2 * 16 + ql];
        uint2 p3 = yb[(size_t)s3 * 16 + ql];
        uint2 p4 = yb[(size_t)s4 * 16 + ql];
        uint2 p5 = yb[(size_t)s5 * 16 + ql];
        uint2 p6 = yb[(size_t)s6 * 16 + ql];
        uint2 p7 = yb[(size_t)s7 * 16 + ql];
        float4 v0 = bf4_to_f4(p0);
        float4 v1 = bf4_to_f4(p1);
        float4 v2 = bf4_to_f4(p2);
        float4 v3 = bf4_to_f4(p3);
        float4 v4 = bf4_to_f4(p4);
        float4 v5 = bf4_to_f4(p5);
        float4 v6 = bf4_to_f4(p6);
        float4 v7 = bf4_to_f4(p7);
        acc.x += v0.x;      acc.y += v0.y;      acc.z += v0.z;      acc.w += v0.w;
        acc.x += v1.x * m1; acc.y += v1.y * m1; acc.z += v1.z * m1; acc.w += v1.w * m1;
        acc.x += v2.x * m2; acc.y += v2.y * m2; acc.z += v2.z * m2; acc.w += v2.w * m2;
        acc.x += v3.x * m3; acc.y += v3.y * m3; acc.z += v3.z * m3; acc.w += v3.w * m3;
        acc.x += v4.x * m4; acc.y += v4.y * m4; acc.z += v4.z * m4; acc.w += v4.w * m4;
        acc.x += v5.x * m5; acc.y += v5.y * m5; acc.z += v5.z * m5; acc.w += v5.w * m5;
        acc.x += v6.x * m6; acc.y += v6.y * m6; acc.z += v6.z * m6; acc.w += v6.w * m6;
        acc.x += v7.x * m7; acc.y += v7.y * m7; acc.z += v7.z * m7; acc.w += v7.w * m7;
    }
    return acc;
}

// ---------------- fused: gather layer l -> prelu -> bf16 LDS -> MFMA transform l+1 ----------------
// 512 threads = 8 waves; gather: 32 nodes x 16 lanes; transform: M=32,N=64,K=64 MFMA.
__global__ __launch_bounds__(512) void fused_gt_kernel(
    const uint2* __restrict__ yb, const float4* __restrict__ z4,
    const int* __restrict__ row_start, const int* __restrict__ deg_cnt,
    const float* __restrict__ deg_inv, const float* __restrict__ alpha,
    const int* __restrict__ csr_src,
    const float* __restrict__ Wl2, const float* __restrict__ Wr2,
    const float* __restrict__ bias2,
    unsigned short* __restrict__ yout, float* __restrict__ zout)
{
    __shared__ unsigned short wlT[64][72];   // Wl^T bf16 [c][k]
    __shared__ unsigned short wrT[64][72];
    __shared__ unsigned short xsb[32][72];   // prelu output, bf16
    __shared__ unsigned short ys[32][64];
    __shared__ float zs[32][64];
    __shared__ float bs2[C];

    int tid = threadIdx.x;
    // stage next-layer weights transposed + bf16 (independent of gather)
    for (int i = tid; i < C * C; i += 512) {
        int k = i >> 6, c = i & 63;
        wlT[c][k] = f2bf(Wl2[i]);
        wrT[c][k] = f2bf(Wr2[i]);
    }
    if (tid < C) bs2[tid] = bias2[tid];

    int nl = tid >> 4;        // 0..31
    int ql = tid & 15;
    int n = blockIdx.x * 32 + nl;

    float4 o = make_float4(0.f, 0.f, 0.f, 0.f);
    if (n < NN) {
        int rs = row_start[n];
        int d = deg_cnt[n];
        float4 acc = gather_row(yb, csr_src + rs, d, ql);
        float di = deg_inv[n];
        float4 zz = z4[(size_t)n * 16 + ql];
        float4 a4 = ((const float4*)alpha)[ql];
        o.x = di * acc.x + zz.x;
        o.y = di * acc.y + zz.y;
        o.z = di * acc.z + zz.z;
        o.w = di * acc.w + zz.w;
        o.x = o.x >= 0.f ? o.x : a4.x * o.x;
        o.y = o.y >= 0.f ? o.y : a4.y * o.y;
        o.z = o.z >= 0.f ? o.z : a4.z * o.z;
        o.w = o.w >= 0.f ? o.w : a4.w * o.w;
    }
    {
        ushort4 p = make_ushort4(f2bf(o.x), f2bf(o.y), f2bf(o.z), f2bf(o.w));
        *(ushort4*)&xsb[nl][ql * 4] = p;
    }
    __syncthreads();

    // MFMA transform: wave w -> mt=w&1, half=(w>>1)&1 (0:y,1:z), ntg=w>>2
    int w = tid >> 6;
    int l = tid & 63;
    int mt = w & 1;
    int half = (w >> 1) & 1;
    int ntg = w >> 2;
    int r16 = l & 15;
    int kg = l >> 4;

    bf16x8 a0 = *(const bf16x8*)&xsb[mt * 16 + r16][kg * 8];
    bf16x8 a1 = *(const bf16x8*)&xsb[mt * 16 + r16][32 + kg * 8];

    #pragma unroll
    for (int q = 0; q < 2; q++) {
        int nt = ntg * 2 + q;
        const unsigned short* col = half ? &wrT[nt * 16 + r16][0] : &wlT[nt * 16 + r16][0];
        bf16x8 b0 = *(const bf16x8*)&col[kg * 8];
        bf16x8 b1 = *(const bf16x8*)&col[32 + kg * 8];
        float bv = half ? bs2[nt * 16 + r16] : 0.f;
        f32x4 acc = (f32x4){bv, bv, bv, bv};
        acc = __builtin_amdgcn_mfma_f32_16x16x32_bf16(a0, b0, acc, 0, 0, 0);
        acc = __builtin_amdgcn_mfma_f32_16x16x32_bf16(a1, b1, acc, 0, 0, 0);
        #pragma unroll
        for (int j = 0; j < 4; j++) {
            int r = mt * 16 + kg * 4 + j;
            int c = nt * 16 + r16;
            if (half) zs[r][c] = acc[j];
            else      ys[r][c] = f2bf(acc[j]);
        }
    }
    __syncthreads();

    // coalesced write-out: 32 rows x 16 chunks = 512 = exactly one pass
    {
        int r = tid >> 4, g = tid & 15;
        int n2 = blockIdx.x * 32 + r;
        if (n2 < NN) {
            ((ushort4*)&yout[(size_t)n2 * C])[g] = ((const ushort4*)&ys[r][0])[g];
            ((float4*)&zout[(size_t)n2 * C])[g] = ((const float4*)&zs[r][0])[g];
        }
    }
}

// ---------------- final gather (layer 3): writes d_out fp32 ----------------
__global__ __launch_bounds__(256) void gather_kernel(
    const uint2* __restrict__ yb, const float4* __restrict__ z4,
    const int* __restrict__ row_start, const int* __restrict__ deg_cnt,
    const float* __restrict__ deg_inv, const float* __restrict__ alpha,
    const int* __restrict__ csr_src,
    float4* __restrict__ out4)
{
    int tid = threadIdx.x;
    int n = blockIdx.x * 16 + (tid >> 4);   // 3125*16 = 50000 exact
    int ql = tid & 15;

    int rs = row_start[n];
    int d = deg_cnt[n];
    float4 acc = gather_row(yb, csr_src + rs, d, ql);

    float di = deg_inv[n];
    float4 zz = z4[(size_t)n * 16 + ql];
    float4 a4 = ((const float4*)alpha)[ql];
    float4 o;
    o.x = di * acc.x + zz.x;
    o.y = di * acc.y + zz.y;
    o.z = di * acc.z + zz.z;
    o.w = di * acc.w + zz.w;
    o.x = o.x >= 0.f ? o.x : a4.x * o.x;
    o.y = o.y >= 0.f ? o.y : a4.y * o.y;
    o.z = o.z >= 0.f ? o.z : a4.z * o.z;
    o.w = o.w >= 0.f ? o.w : a4.w * o.w;
    out4[(size_t)n * 16 + ql] = o;
}

extern "C" void kernel_launch(void* const* d_in, const int* in_sizes, int n_in,
                              void* d_out, int out_size, void* d_ws, size_t ws_size,
                              hipStream_t stream) {
    const float* x     = (const float*)d_in[0];
    const int*   ei    = (const int*)d_in[1];
    const float* Wl    = (const float*)d_in[2];
    const float* Wr    = (const float*)d_in[3];
    const float* b     = (const float*)d_in[4];
    const float* alpha = (const float*)d_in[5];
    float* out = (float*)d_out;

    const int* src = ei;        // edge_index[0]
    const int* dst = ei + NE;   // edge_index[1]

    // workspace layout (all blocks 16B-aligned)
    char* wsp = (char*)d_ws;
    int*   deg_cnt   = (int*)wsp;                   wsp += (size_t)(NN + 16) * 4;
    float* deg_inv   = (float*)wsp;                 wsp += (size_t)NN * 4;
    int*   row_start = (int*)wsp;                   wsp += (size_t)NN * 4;
    int*   bsums     = (int*)wsp;                   wsp += 1024;
    int*   rankb     = (int*)wsp;                   wsp += (size_t)NE * 4;
    int*   csr_src   = (int*)wsp;                   wsp += (size_t)NE * 4;
    unsigned short* y0buf = (unsigned short*)wsp;   wsp += (size_t)NN * C * 2;
    unsigned short* y1buf = (unsigned short*)wsp;   wsp += (size_t)NN * C * 2;
    float* z0buf     = (float*)wsp;                 wsp += (size_t)NN * C * 4;
    float* z1buf     = (float*)wsp;

    // ---- CSR build ----
    init_kernel<<<49, 256, 0, stream>>>((int4*)deg_cnt);
    hist_rank_kernel<<<(NE + 255) / 256, 256, 0, stream>>>(dst, deg_cnt, rankb);
    scan1_kernel<<<SCAN_NB, 256, 0, stream>>>(deg_cnt, row_start, bsums);
    scan23_kernel<<<SCAN_NB, 256, 0, stream>>>(row_start, bsums, deg_cnt, deg_inv);
    fill_kernel<<<(NE / 4 + 255) / 256, 256, 0, stream>>>(src, dst, rankb, row_start, csr_src);

    // ---- layer-0 transform (MFMA) ----
    transform_mfma_kernel<<<(NN + 63) / 64, 512, 0, stream>>>(x, Wl, Wr, b, y0buf, z0buf);

    // ---- fused (gather_l + MFMA transform_{l+1}) for l = 0,1,2; ping-pong ----
    const int fblocks = (NN + 31) / 32;
    unsigned short* ycur = y0buf; float* zcur = z0buf;
    unsigned short* ynxt = y1buf; float* znxt = z1buf;
    for (int l = 0; l < NL - 1; l++) {
        fused_gt_kernel<<<fblocks, 512, 0, stream>>>(
            (const uint2*)ycur, (const float4*)zcur,
            row_start, deg_cnt, deg_inv, alpha + (size_t)l * C, csr_src,
            Wl + (size_t)(l + 1) * C * C, Wr + (size_t)(l + 1) * C * C,
            b + (size_t)(l + 1) * C,
            ynxt, znxt);
        unsigned short* ty = ycur; float* tz = zcur;
        ycur = ynxt; zcur = znxt;
        ynxt = ty;   znxt = tz;
    }

    // ---- final gather (layer 3) -> d_out ----
    gather_kernel<<<NN / 16, 256, 0, stream>>>(
        (const uint2*)ycur, (const float4*)zcur, row_start, deg_cnt,
        deg_inv, alpha + (size_t)(NL - 1) * C, csr_src, (float4*)out);
}

// Round 15
// 163.879 us; speedup vs baseline: 1.2381x; 1.0508x over previous
//
#include <hip/hip_runtime.h>

#define NN 50000
#define NE 800000
#define C 64
#define NL 4
#define SCAN_NB 196        // ceil(50000/256)
#define NBK 196            // buckets = ceil(NN/256)
#define HBLK 782           // ceil(NE/1024) blocks for bucket hist/scatter

typedef __attribute__((ext_vector_type(8))) short bf16x8;
typedef __attribute__((ext_vector_type(4))) float f32x4;

// ---- bf16 helpers (RNE) ----
__device__ __forceinline__ unsigned short f2bf(float f) {
    unsigned u = __float_as_uint(f);
    u += 0x7fffu + ((u >> 16) & 1u);
    return (unsigned short)(u >> 16);
}
__device__ __forceinline__ float4 bf4_to_f4(uint2 p) {
    float4 r;
    r.x = __uint_as_float(p.x << 16);
    r.y = __uint_as_float(p.x & 0xffff0000u);
    r.z = __uint_as_float(p.y << 16);
    r.w = __uint_as_float(p.y & 0xffff0000u);
    return r;
}

// ---------------- K1: per-block LDS bucket histogram + local rank ----------------
__global__ __launch_bounds__(1024) void bucket_hist_kernel(const int* __restrict__ dst,
                                                           int* __restrict__ blk_cnt,
                                                           int* __restrict__ lrank) {
    __shared__ int cnt[NBK];
    int tid = threadIdx.x;
    int blk = blockIdx.x;
    if (tid < NBK) cnt[tid] = 0;
    __syncthreads();
    int e = blk * 1024 + tid;
    if (e < NE) lrank[e] = atomicAdd(&cnt[dst[e] >> 8], 1);
    __syncthreads();
    if (tid < NBK) blk_cnt[tid * HBLK + blk] = cnt[tid];   // layout [bucket][blk]
}

// ---------------- K2: per-bucket exclusive scan over its 782 block counts ----------------
__global__ __launch_bounds__(1024) void scanblk_kernel(int* __restrict__ blk_cnt,
                                                       int* __restrict__ bucket_tot) {
    __shared__ int sdata[1024];
    int b = blockIdx.x;
    int tid = threadIdx.x;
    int v = (tid < HBLK) ? blk_cnt[b * HBLK + tid] : 0;
    sdata[tid] = v;
    __syncthreads();
    for (int off = 1; off < 1024; off <<= 1) {
        int t = (tid >= off) ? sdata[tid - off] : 0;
        __syncthreads();
        sdata[tid] += t;
        __syncthreads();
    }
    if (tid < HBLK) blk_cnt[b * HBLK + tid] = sdata[tid] - v;   // exclusive, in place
    if (tid == HBLK - 1) bucket_tot[b] = sdata[tid];
}

// ---------------- K2b: scan bucket totals -> bucket_start (197 entries) ----------------
__global__ __launch_bounds__(256) void scanbucket_kernel(const int* __restrict__ bucket_tot,
                                                         int* __restrict__ bucket_start) {
    __shared__ int sdata[256];
    int tid = threadIdx.x;
    int v = (tid < NBK) ? bucket_tot[tid] : 0;
    sdata[tid] = v;
    __syncthreads();
    for (int off = 1; off < 256; off <<= 1) {
        int t = (tid >= off) ? sdata[tid - off] : 0;
        __syncthreads();
        sdata[tid] += t;
        __syncthreads();
    }
    if (tid < NBK) bucket_start[tid] = sdata[tid] - v;
    if (tid == NBK - 1) bucket_start[NBK] = sdata[tid];   // = NE
}

// ---------------- K3: scatter edges into bucket-sorted order ----------------
__global__ __launch_bounds__(1024) void bucket_scatter_kernel(
    const int* __restrict__ src, const int* __restrict__ dst,
    const int* __restrict__ lrank, const int* __restrict__ base2,
    const int* __restrict__ bucket_start, int2* __restrict__ sorted) {
    int blk = blockIdx.x;
    int e = blk * 1024 + threadIdx.x;
    if (e < NE) {
        int d = dst[e];
        int b = d >> 8;
        int pos = bucket_start[b] + base2[b * HBLK + blk] + lrank[e];
        sorted[pos] = make_int2(src[e], d);
    }
}

// ---------------- K4a: per-bucket degree count (LDS, no rank) ----------------
__global__ __launch_bounds__(512) void bucket_deg_kernel(const int2* __restrict__ sorted,
                                                         const int* __restrict__ bucket_start,
                                                         int* __restrict__ deg) {
    __shared__ int ldeg[256];
    int b = blockIdx.x;
    int tid = threadIdx.x;
    if (tid < 256) ldeg[tid] = 0;
    __syncthreads();
    int lo = bucket_start[b], hi = bucket_start[b + 1];
    for (int i = lo + tid; i < hi; i += 512)
        atomicAdd(&ldeg[sorted[i].y & 255], 1);
    __syncthreads();
    if (tid < 256) deg[b * 256 + tid] = ldeg[tid];
}

// ---------------- scan1: exclusive scan of deg -> row_start (within block) ----------------
__global__ __launch_bounds__(256) void scan1_kernel(const int* __restrict__ deg,
                                                    int* __restrict__ row_start,
                                                    int* __restrict__ bsums) {
    __shared__ int sdata[256];
    int tid = threadIdx.x;
    int i = blockIdx.x * 256 + tid;
    int v = (i < NN) ? deg[i] : 0;
    sdata[tid] = v;
    __syncthreads();
    for (int off = 1; off < 256; off <<= 1) {
        int t = (tid >= off) ? sdata[tid - off] : 0;
        __syncthreads();
        sdata[tid] += t;
        __syncthreads();
    }
    int incl = sdata[tid];
    if (i < NN) row_start[i] = incl - v;
    if (tid == 255) bsums[blockIdx.x] = incl;
}

// ---------------- scan23: apply block offsets + deg_inv ----------------
__global__ __launch_bounds__(256) void scan23_kernel(int* __restrict__ row_start,
                                                     const int* __restrict__ bsums,
                                                     const int* __restrict__ deg,
                                                     float* __restrict__ deg_inv) {
    __shared__ int sdata[256];
    int tid = threadIdx.x;
    int v = (tid < SCAN_NB) ? bsums[tid] : 0;
    sdata[tid] = v;
    __syncthreads();
    for (int off = 1; off < 256; off <<= 1) {
        int t = (tid >= off) ? sdata[tid - off] : 0;
        __syncthreads();
        sdata[tid] += t;
        __syncthreads();
    }
    int b = blockIdx.x;
    int offset = (b == 0) ? 0 : sdata[b - 1];
    int i = b * 256 + tid;
    if (i < NN) {
        row_start[i] += offset;
        deg_inv[i] = 1.0f / fmaxf((float)deg[i], 1.0f);
    }
}

// ---------------- K4b: per-bucket CSR fill (LDS ranks, L2-local row writes) ----------------
__global__ __launch_bounds__(512) void bucket_fill_kernel(const int2* __restrict__ sorted,
                                                          const int* __restrict__ bucket_start,
                                                          const int* __restrict__ row_start,
                                                          int* __restrict__ csr_src) {
    __shared__ int rs[256];
    __shared__ int lcnt[256];
    int b = blockIdx.x;
    int tid = threadIdx.x;
    if (tid < 256) {
        int n = b * 256 + tid;
        rs[tid] = (n < NN) ? row_start[n] : 0;
        lcnt[tid] = 0;
    }
    __syncthreads();
    int lo = bucket_start[b], hi = bucket_start[b + 1];
    for (int i = lo + tid; i < hi; i += 512) {
        int2 p = sorted[i];
        int r = atomicAdd(&lcnt[p.y & 255], 1);
        csr_src[rs[p.y & 255] + r] = p.x;
    }
}

// ---------------- layer-0 transform via MFMA (validated R13) ----------------
__global__ __launch_bounds__(512) void transform_mfma_kernel(
    const float* __restrict__ xin,
    const float* __restrict__ Wl, const float* __restrict__ Wr,
    const float* __restrict__ bias,
    unsigned short* __restrict__ y, float* __restrict__ z)
{
    __shared__ unsigned short xs[64][72];
    __shared__ unsigned short wlT[64][72];
    __shared__ unsigned short wrT[64][72];
    __shared__ unsigned short ys[64][64];
    __shared__ float zs[64][64];
    __shared__ float bs[C];

    int tid = threadIdx.x;
    int node0 = blockIdx.x * 64;

    for (int i = tid; i < C * C; i += 512) {
        int k = i >> 6, c = i & 63;
        wlT[c][k] = f2bf(Wl[i]);
        wrT[c][k] = f2bf(Wr[i]);
    }
    if (tid < C) bs[tid] = bias[tid];
    for (int i = tid; i < 64 * 16; i += 512) {
        int nl = i >> 4, c4 = i & 15;
        int n = node0 + nl;
        int nc = n < NN ? n : NN - 1;
        float4 v = ((const float4*)xin)[(size_t)nc * 16 + c4];
        xs[nl][c4 * 4 + 0] = f2bf(v.x);
        xs[nl][c4 * 4 + 1] = f2bf(v.y);
        xs[nl][c4 * 4 + 2] = f2bf(v.z);
        xs[nl][c4 * 4 + 3] = f2bf(v.w);
    }
    __syncthreads();

    int w = tid >> 6;
    int l = tid & 63;
    int mt = w >> 1;
    int half = w & 1;
    int r16 = l & 15;
    int kg = l >> 4;

    bf16x8 a0 = *(const bf16x8*)&xs[mt * 16 + r16][kg * 8];
    bf16x8 a1 = *(const bf16x8*)&xs[mt * 16 + r16][32 + kg * 8];

    f32x4 acc[4];
    #pragma unroll
    for (int nt = 0; nt < 4; nt++) {
        float bv = half ? bs[nt * 16 + r16] : 0.f;
        acc[nt] = (f32x4){bv, bv, bv, bv};
    }
    #pragma unroll
    for (int nt = 0; nt < 4; nt++) {
        const unsigned short* col = half ? &wrT[nt * 16 + r16][0] : &wlT[nt * 16 + r16][0];
        bf16x8 b0 = *(const bf16x8*)&col[kg * 8];
        bf16x8 b1 = *(const bf16x8*)&col[32 + kg * 8];
        acc[nt] = __builtin_amdgcn_mfma_f32_16x16x32_bf16(a0, b0, acc[nt], 0, 0, 0);
        acc[nt] = __builtin_amdgcn_mfma_f32_16x16x32_bf16(a1, b1, acc[nt], 0, 0, 0);
    }
    #pragma unroll
    for (int nt = 0; nt < 4; nt++) {
        #pragma unroll
        for (int j = 0; j < 4; j++) {
            int r = mt * 16 + kg * 4 + j;
            int c = nt * 16 + r16;
            if (half) zs[r][c] = acc[nt][j];
            else      ys[r][c] = f2bf(acc[nt][j]);
        }
    }
    __syncthreads();

    for (int i = tid; i < 64 * 16; i += 512) {
        int r = i >> 4, g = i & 15;
        int n = node0 + r;
        if (n < NN) {
            ((ushort4*)&y[(size_t)n * C])[g] = ((const ushort4*)&ys[r][0])[g];
            ((float4*)&z[(size_t)n * C])[g] = ((const float4*)&zs[r][0])[g];
        }
    }
}

// ---------------- gather core: bf16 rows, masked unroll-8 ----------------
__device__ __forceinline__ float4 gather_row(const uint2* __restrict__ yb,
                                             const int* __restrict__ cp, int d, int ql) {
    float4 acc = make_float4(0.f, 0.f, 0.f, 0.f);
    for (int t = 0; t < d; t += 8) {
        int lim = d - 1 - t;
        int j1 = min(1, lim), j2 = min(2, lim), j3 = min(3, lim);
        int j4 = min(4, lim), j5 = min(5, lim), j6 = min(6, lim), j7 = min(7, lim);
        float m1 = lim >= 1 ? 1.f : 0.f, m2 = lim >= 2 ? 1.f : 0.f;
        float m3 = lim >= 3 ? 1.f : 0.f, m4 = lim >= 4 ? 1.f : 0.f;
        float m5 = lim >= 5 ? 1.f : 0.f, m6 = lim >= 6 ? 1.f : 0.f;
        float m7 = lim >= 7 ? 1.f : 0.f;
        int s0 = cp[t];
        int s1 = cp[t + j1];
        int s2 = cp[t + j2];
        int s3 = cp[t + j3];
        int s4 = cp[t + j4];
        int s5 = cp[t + j5];
        int s6 = cp[t + j6];
        int s7 = cp[t + j7];
        uint2 p0 = yb[(size_t)s0 * 16 + ql];
        uint2 p1 = yb[(size_t)s1 * 16 + ql];
        uint2 p2 = yb[(size_t)s2 * 16 + ql];
        uint2 p3 = yb[(size_t)s3 * 16 + ql];
        uint2 p4 = yb[(size_t)s4 * 16 + ql];
        uint2 p5 = yb[(size_t)s5 * 16 + ql];
        uint2 p6 = yb[(size_t)s6 * 16 + ql];
        uint2 p7 = yb[(size_t)s7 * 16 + ql];
        float4 v0 = bf4_to_f4(p0);
        float4 v1 = bf4_to_f4(p1);
        float4 v2 = bf4_to_f4(p2);
        float4 v3 = bf4_to_f4(p3);
        float4 v4 = bf4_to_f4(p4);
        float4 v5 = bf4_to_f4(p5);
        float4 v6 = bf4_to_f4(p6);
        float4 v7 = bf4_to_f4(p7);
        acc.x += v0.x;      acc.y += v0.y;      acc.z += v0.z;      acc.w += v0.w;
        acc.x += v1.x * m1; acc.y += v1.y * m1; acc.z += v1.z * m1; acc.w += v1.w * m1;
        acc.x += v2.x * m2; acc.y += v2.y * m2; acc.z += v2.z * m2; acc.w += v2.w * m2;
        acc.x += v3.x * m3; acc.y += v3.y * m3; acc.z += v3.z * m3; acc.w += v3.w * m3;
        acc.x += v4.x * m4; acc.y += v4.y * m4; acc.z += v4.z * m4; acc.w += v4.w * m4;
        acc.x += v5.x * m5; acc.y += v5.y * m5; acc.z += v5.z * m5; acc.w += v5.w * m5;
        acc.x += v6.x * m6; acc.y += v6.y * m6; acc.z += v6.z * m6; acc.w += v6.w * m6;
        acc.x += v7.x * m7; acc.y += v7.y * m7; acc.z += v7.z * m7; acc.w += v7.w * m7;
    }
    return acc;
}

// ---------------- fused: gather layer l -> prelu -> bf16 LDS -> MFMA transform l+1 ----------------
__global__ __launch_bounds__(512) void fused_gt_kernel(
    const uint2* __restrict__ yb, const float4* __restrict__ z4,
    const int* __restrict__ row_start, const int* __restrict__ deg,
    const float* __restrict__ deg_inv, const float* __restrict__ alpha,
    const int* __restrict__ csr_src,
    const float* __restrict__ Wl2, const float* __restrict__ Wr2,
    const float* __restrict__ bias2,
    unsigned short* __restrict__ yout, float* __restrict__ zout)
{
    __shared__ unsigned short wlT[64][72];
    __shared__ unsigned short wrT[64][72];
    __shared__ unsigned short xsb[32][72];
    __shared__ unsigned short ys[32][64];
    __shared__ float zs[32][64];
    __shared__ float bs2[C];

    int tid = threadIdx.x;
    for (int i = tid; i < C * C; i += 512) {
        int k = i >> 6, c = i & 63;
        wlT[c][k] = f2bf(Wl2[i]);
        wrT[c][k] = f2bf(Wr2[i]);
    }
    if (tid < C) bs2[tid] = bias2[tid];

    int nl = tid >> 4;
    int ql = tid & 15;
    int n = blockIdx.x * 32 + nl;

    float4 o = make_float4(0.f, 0.f, 0.f, 0.f);
    if (n < NN) {
        int rs = row_start[n];
        int d = deg[n];
        float4 acc = gather_row(yb, csr_src + rs, d, ql);
        float di = deg_inv[n];
        float4 zz = z4[(size_t)n * 16 + ql];
        float4 a4 = ((const float4*)alpha)[ql];
        o.x = di * acc.x + zz.x;
        o.y = di * acc.y + zz.y;
        o.z = di * acc.z + zz.z;
        o.w = di * acc.w + zz.w;
        o.x = o.x >= 0.f ? o.x : a4.x * o.x;
        o.y = o.y >= 0.f ? o.y : a4.y * o.y;
        o.z = o.z >= 0.f ? o.z : a4.z * o.z;
        o.w = o.w >= 0.f ? o.w : a4.w * o.w;
    }
    {
        ushort4 p = make_ushort4(f2bf(o.x), f2bf(o.y), f2bf(o.z), f2bf(o.w));
        *(ushort4*)&xsb[nl][ql * 4] = p;
    }
    __syncthreads();

    int w = tid >> 6;
    int l = tid & 63;
    int mt = w & 1;
    int half = (w >> 1) & 1;
    int ntg = w >> 2;
    int r16 = l & 15;
    int kg = l >> 4;

    bf16x8 a0 = *(const bf16x8*)&xsb[mt * 16 + r16][kg * 8];
    bf16x8 a1 = *(const bf16x8*)&xsb[mt * 16 + r16][32 + kg * 8];

    #pragma unroll
    for (int q = 0; q < 2; q++) {
        int nt = ntg * 2 + q;
        const unsigned short* col = half ? &wrT[nt * 16 + r16][0] : &wlT[nt * 16 + r16][0];
        bf16x8 b0 = *(const bf16x8*)&col[kg * 8];
        bf16x8 b1 = *(const bf16x8*)&col[32 + kg * 8];
        float bv = half ? bs2[nt * 16 + r16] : 0.f;
        f32x4 acc = (f32x4){bv, bv, bv, bv};
        acc = __builtin_amdgcn_mfma_f32_16x16x32_bf16(a0, b0, acc, 0, 0, 0);
        acc = __builtin_amdgcn_mfma_f32_16x16x32_bf16(a1, b1, acc, 0, 0, 0);
        #pragma unroll
        for (int j = 0; j < 4; j++) {
            int r = mt * 16 + kg * 4 + j;
            int c = nt * 16 + r16;
            if (half) zs[r][c] = acc[j];
            else      ys[r][c] = f2bf(acc[j]);
        }
    }
    __syncthreads();

    {
        int r = tid >> 4, g = tid & 15;
        int n2 = blockIdx.x * 32 + r;
        if (n2 < NN) {
            ((ushort4*)&yout[(size_t)n2 * C])[g] = ((const ushort4*)&ys[r][0])[g];
            ((float4*)&zout[(size_t)n2 * C])[g] = ((const float4*)&zs[r][0])[g];
        }
    }
}

// ---------------- final gather (layer 3): writes d_out fp32 ----------------
__global__ __launch_bounds__(256) void gather_kernel(
    const uint2* __restrict__ yb, const float4* __restrict__ z4,
    const int* __restrict__ row_start, const int* __restrict__ deg,
    const float* __restrict__ deg_inv, const float* __restrict__ alpha,
    const int* __restrict__ csr_src,
    float4* __restrict__ out4)
{
    int tid = threadIdx.x;
    int n = blockIdx.x * 16 + (tid >> 4);
    int ql = tid & 15;

    int rs = row_start[n];
    int d = deg[n];
    float4 acc = gather_row(yb, csr_src + rs, d, ql);

    float di = deg_inv[n];
    float4 zz = z4[(size_t)n * 16 + ql];
    float4 a4 = ((const float4*)alpha)[ql];
    float4 o;
    o.x = di * acc.x + zz.x;
    o.y = di * acc.y + zz.y;
    o.z = di * acc.z + zz.z;
    o.w = di * acc.w + zz.w;
    o.x = o.x >= 0.f ? o.x : a4.x * o.x;
    o.y = o.y >= 0.f ? o.y : a4.y * o.y;
    o.z = o.z >= 0.f ? o.z : a4.z * o.z;
    o.w = o.w >= 0.f ? o.w : a4.w * o.w;
    out4[(size_t)n * 16 + ql] = o;
}

extern "C" void kernel_launch(void* const* d_in, const int* in_sizes, int n_in,
                              void* d_out, int out_size, void* d_ws, size_t ws_size,
                              hipStream_t stream) {
    const float* x     = (const float*)d_in[0];
    const int*   ei    = (const int*)d_in[1];
    const float* Wl    = (const float*)d_in[2];
    const float* Wr    = (const float*)d_in[3];
    const float* b     = (const float*)d_in[4];
    const float* alpha = (const float*)d_in[5];
    float* out = (float*)d_out;

    const int* src = ei;        // edge_index[0]
    const int* dst = ei + NE;   // edge_index[1]

    // workspace layout (all 16B-aligned; everything fully rewritten each call)
    char* wsp = (char*)d_ws;
    int*  lrank        = (int*)wsp;                 wsp += (size_t)NE * 4;        // aliased by csr_src
    int*  blk_cnt      = (int*)wsp;                 wsp += (size_t)NBK * HBLK * 4 + 256;
    int*  bucket_tot   = (int*)wsp;                 wsp += 1024;
    int*  bucket_start = (int*)wsp;                 wsp += 1024;
    int2* sorted       = (int2*)wsp;                wsp += (size_t)NE * 8;
    int*  deg          = (int*)wsp;                 wsp += (size_t)(NBK * 256) * 4;
    float* deg_inv     = (float*)wsp;               wsp += (size_t)NN * 4;
    int*  row_start    = (int*)wsp;                 wsp += (size_t)NN * 4;
    int*  bsums        = (int*)wsp;                 wsp += 1024;
    unsigned short* y0buf = (unsigned short*)wsp;   wsp += (size_t)NN * C * 2;
    unsigned short* y1buf = (unsigned short*)wsp;   wsp += (size_t)NN * C * 2;
    float* z0buf       = (float*)wsp;               wsp += (size_t)NN * C * 4;
    float* z1buf       = (float*)wsp;
    int*  csr_src      = lrank;   // lrank dead after bucket_scatter; csr written after

    // ---- CSR build: bucket-sorted, LDS-atomic only ----
    bucket_hist_kernel<<<HBLK, 1024, 0, stream>>>(dst, blk_cnt, lrank);
    scanblk_kernel<<<NBK, 1024, 0, stream>>>(blk_cnt, bucket_tot);
    scanbucket_kernel<<<1, 256, 0, stream>>>(bucket_tot, bucket_start);
    bucket_scatter_kernel<<<HBLK, 1024, 0, stream>>>(src, dst, lrank, blk_cnt,
                                                     bucket_start, sorted);
    bucket_deg_kernel<<<NBK, 512, 0, stream>>>(sorted, bucket_start, deg);
    scan1_kernel<<<SCAN_NB, 256, 0, stream>>>(deg, row_start, bsums);
    scan23_kernel<<<SCAN_NB, 256, 0, stream>>>(row_start, bsums, deg, deg_inv);
    bucket_fill_kernel<<<NBK, 512, 0, stream>>>(sorted, bucket_start, row_start, csr_src);

    // ---- layer-0 transform (MFMA) ----
    transform_mfma_kernel<<<(NN + 63) / 64, 512, 0, stream>>>(x, Wl, Wr, b, y0buf, z0buf);

    // ---- fused (gather_l + MFMA transform_{l+1}) for l = 0,1,2; ping-pong ----
    const int fblocks = (NN + 31) / 32;
    unsigned short* ycur = y0buf; float* zcur = z0buf;
    unsigned short* ynxt = y1buf; float* znxt = z1buf;
    for (int l = 0; l < NL - 1; l++) {
        fused_gt_kernel<<<fblocks, 512, 0, stream>>>(
            (const uint2*)ycur, (const float4*)zcur,
            row_start, deg, deg_inv, alpha + (size_t)l * C, csr_src,
            Wl + (size_t)(l + 1) * C * C, Wr + (size_t)(l + 1) * C * C,
            b + (size_t)(l + 1) * C,
            ynxt, znxt);
        unsigned short* ty = ycur; float* tz = zcur;
        ycur = ynxt; zcur = znxt;
        ynxt = ty;   znxt = tz;
    }

    // ---- final gather (layer 3) -> d_out ----
    gather_kernel<<<NN / 16, 256, 0, stream>>>(
        (const uint2*)ycur, (const float4*)zcur, row_start, deg,
        deg_inv, alpha + (size_t)(NL - 1) * C, csr_src, (float4*)out);
}

// Round 16
// 158.305 us; speedup vs baseline: 1.2817x; 1.0352x over previous
//
#include <hip/hip_runtime.h>

#define NN 50000
#define NE 800000
#define C 64
#define NL 4
#define NBK 196            // buckets = ceil(NN/256)
#define HBLK 782           // ceil(NE/1024) blocks for bucket hist/scatter

typedef __attribute__((ext_vector_type(8))) short bf16x8;
typedef __attribute__((ext_vector_type(4))) float f32x4;

// ---- bf16 helpers (RNE) ----
__device__ __forceinline__ unsigned short f2bf(float f) {
    unsigned u = __float_as_uint(f);
    u += 0x7fffu + ((u >> 16) & 1u);
    return (unsigned short)(u >> 16);
}
__device__ __forceinline__ float4 bf4_to_f4(uint2 p) {
    float4 r;
    r.x = __uint_as_float(p.x << 16);
    r.y = __uint_as_float(p.x & 0xffff0000u);
    r.z = __uint_as_float(p.y << 16);
    r.w = __uint_as_float(p.y & 0xffff0000u);
    return r;
}

// ---------------- K1: per-block LDS bucket histogram + local rank ----------------
__global__ __launch_bounds__(1024) void bucket_hist_kernel(const int* __restrict__ dst,
                                                           int* __restrict__ blk_cnt,
                                                           int* __restrict__ lrank) {
    __shared__ int cnt[NBK];
    int tid = threadIdx.x;
    int blk = blockIdx.x;
    if (tid < NBK) cnt[tid] = 0;
    __syncthreads();
    int e = blk * 1024 + tid;
    if (e < NE) lrank[e] = atomicAdd(&cnt[dst[e] >> 8], 1);
    __syncthreads();
    if (tid < NBK) blk_cnt[tid * HBLK + blk] = cnt[tid];   // layout [bucket][blk]
}

// ---------------- K2: per-bucket exclusive scan over its 782 block counts ----------------
__global__ __launch_bounds__(1024) void scanblk_kernel(int* __restrict__ blk_cnt,
                                                       int* __restrict__ bucket_tot) {
    __shared__ int sdata[1024];
    int b = blockIdx.x;
    int tid = threadIdx.x;
    int v = (tid < HBLK) ? blk_cnt[b * HBLK + tid] : 0;
    sdata[tid] = v;
    __syncthreads();
    for (int off = 1; off < 1024; off <<= 1) {
        int t = (tid >= off) ? sdata[tid - off] : 0;
        __syncthreads();
        sdata[tid] += t;
        __syncthreads();
    }
    if (tid < HBLK) blk_cnt[b * HBLK + tid] = sdata[tid] - v;   // exclusive, in place
    if (tid == HBLK - 1) bucket_tot[b] = sdata[tid];
}

// ---------------- K3: scatter edges into bucket-sorted order ----------------
// bucket_start derived redundantly per block from bucket_tot (196-entry LDS scan).
__global__ __launch_bounds__(1024) void bucket_scatter_kernel(
    const int* __restrict__ src, const int* __restrict__ dst,
    const int* __restrict__ lrank, const int* __restrict__ base2,
    const int* __restrict__ bucket_tot, int2* __restrict__ sorted) {
    __shared__ int sscan[256];
    __shared__ int sex[256];
    int tid = threadIdx.x;
    int blk = blockIdx.x;
    int v0 = 0;
    if (tid < 256) {
        v0 = (tid < NBK) ? bucket_tot[tid] : 0;
        sscan[tid] = v0;
    }
    __syncthreads();
    for (int off = 1; off < 256; off <<= 1) {
        int t = (tid < 256 && tid >= off) ? sscan[tid - off] : 0;
        __syncthreads();
        if (tid < 256) sscan[tid] += t;
        __syncthreads();
    }
    if (tid < 256) sex[tid] = sscan[tid] - v0;   // exclusive bucket start
    __syncthreads();

    int e = blk * 1024 + tid;
    if (e < NE) {
        int d = dst[e];
        int b = d >> 8;
        int pos = sex[b] + base2[b * HBLK + blk] + lrank[e];
        sorted[pos] = make_int2(src[e], d);
    }
}

// ---------------- K4: per-bucket finalize: deg count + local scan + row_start/deg_inv + CSR fill ----------------
// row_start[n] = bucket_start[b] + exclusive_scan_within_bucket(deg)  (bucket-sort invariant)
__global__ __launch_bounds__(512) void bucket_finalize_kernel(
    const int2* __restrict__ sorted, const int* __restrict__ bucket_tot,
    int* __restrict__ row_start, int* __restrict__ deg, float* __restrict__ deg_inv,
    int* __restrict__ csr_src) {
    __shared__ int sscan[256];
    __shared__ int ldeg[256];
    __shared__ int lpre[256];
    __shared__ int lcnt[256];

    int b = blockIdx.x;
    int tid = threadIdx.x;
    int v0 = 0;
    if (tid < 256) {
        v0 = (tid < NBK) ? bucket_tot[tid] : 0;
        sscan[tid] = v0;
        ldeg[tid] = 0;
        lcnt[tid] = 0;
    }
    __syncthreads();
    for (int off = 1; off < 256; off <<= 1) {
        int t = (tid < 256 && tid >= off) ? sscan[tid - off] : 0;
        __syncthreads();
        if (tid < 256) sscan[tid] += t;
        __syncthreads();
    }
    int lo = (b == 0) ? 0 : sscan[b - 1];
    int hi = sscan[b];
    __syncthreads();

    // degree count within bucket (LDS atomics)
    for (int i = lo + tid; i < hi; i += 512)
        atomicAdd(&ldeg[sorted[i].y & 255], 1);
    __syncthreads();

    // exclusive scan of ldeg within bucket
    int dv = 0;
    if (tid < 256) {
        dv = ldeg[tid];
        lpre[tid] = dv;
    }
    __syncthreads();
    for (int off = 1; off < 256; off <<= 1) {
        int t = (tid < 256 && tid >= off) ? lpre[tid - off] : 0;
        __syncthreads();
        if (tid < 256) lpre[tid] += t;
        __syncthreads();
    }
    if (tid < 256) {
        int p = lpre[tid] - dv;      // exclusive
        lpre[tid] = p;
        int n = b * 256 + tid;
        if (n < NN) {
            row_start[n] = lo + p;
            deg[n] = dv;
            deg_inv[n] = 1.0f / fmaxf((float)dv, 1.0f);
        }
    }
    __syncthreads();

    // CSR fill (LDS ranks; row writes are contiguous runs)
    for (int i = lo + tid; i < hi; i += 512) {
        int2 p = sorted[i];
        int loc = p.y & 255;
        int r = atomicAdd(&lcnt[loc], 1);
        csr_src[lo + lpre[loc] + r] = p.x;
    }
}

// ---------------- layer-0 transform via MFMA (validated R13) ----------------
__global__ __launch_bounds__(512) void transform_mfma_kernel(
    const float* __restrict__ xin,
    const float* __restrict__ Wl, const float* __restrict__ Wr,
    const float* __restrict__ bias,
    unsigned short* __restrict__ y, float* __restrict__ z)
{
    __shared__ unsigned short xs[64][72];
    __shared__ unsigned short wlT[64][72];
    __shared__ unsigned short wrT[64][72];
    __shared__ unsigned short ys[64][64];
    __shared__ float zs[64][64];
    __shared__ float bs[C];

    int tid = threadIdx.x;
    int node0 = blockIdx.x * 64;

    for (int i = tid; i < C * C; i += 512) {
        int k = i >> 6, c = i & 63;
        wlT[c][k] = f2bf(Wl[i]);
        wrT[c][k] = f2bf(Wr[i]);
    }
    if (tid < C) bs[tid] = bias[tid];
    for (int i = tid; i < 64 * 16; i += 512) {
        int nl = i >> 4, c4 = i & 15;
        int n = node0 + nl;
        int nc = n < NN ? n : NN - 1;
        float4 v = ((const float4*)xin)[(size_t)nc * 16 + c4];
        xs[nl][c4 * 4 + 0] = f2bf(v.x);
        xs[nl][c4 * 4 + 1] = f2bf(v.y);
        xs[nl][c4 * 4 + 2] = f2bf(v.z);
        xs[nl][c4 * 4 + 3] = f2bf(v.w);
    }
    __syncthreads();

    int w = tid >> 6;
    int l = tid & 63;
    int mt = w >> 1;
    int half = w & 1;
    int r16 = l & 15;
    int kg = l >> 4;

    bf16x8 a0 = *(const bf16x8*)&xs[mt * 16 + r16][kg * 8];
    bf16x8 a1 = *(const bf16x8*)&xs[mt * 16 + r16][32 + kg * 8];

    f32x4 acc[4];
    #pragma unroll
    for (int nt = 0; nt < 4; nt++) {
        float bv = half ? bs[nt * 16 + r16] : 0.f;
        acc[nt] = (f32x4){bv, bv, bv, bv};
    }
    #pragma unroll
    for (int nt = 0; nt < 4; nt++) {
        const unsigned short* col = half ? &wrT[nt * 16 + r16][0] : &wlT[nt * 16 + r16][0];
        bf16x8 b0 = *(const bf16x8*)&col[kg * 8];
        bf16x8 b1 = *(const bf16x8*)&col[32 + kg * 8];
        acc[nt] = __builtin_amdgcn_mfma_f32_16x16x32_bf16(a0, b0, acc[nt], 0, 0, 0);
        acc[nt] = __builtin_amdgcn_mfma_f32_16x16x32_bf16(a1, b1, acc[nt], 0, 0, 0);
    }
    #pragma unroll
    for (int nt = 0; nt < 4; nt++) {
        #pragma unroll
        for (int j = 0; j < 4; j++) {
            int r = mt * 16 + kg * 4 + j;
            int c = nt * 16 + r16;
            if (half) zs[r][c] = acc[nt][j];
            else      ys[r][c] = f2bf(acc[nt][j]);
        }
    }
    __syncthreads();

    for (int i = tid; i < 64 * 16; i += 512) {
        int r = i >> 4, g = i & 15;
        int n = node0 + r;
        if (n < NN) {
            ((ushort4*)&y[(size_t)n * C])[g] = ((const ushort4*)&ys[r][0])[g];
            ((float4*)&z[(size_t)n * C])[g] = ((const float4*)&zs[r][0])[g];
        }
    }
}

// ---------------- gather core: bf16 rows, masked unroll-8 ----------------
__device__ __forceinline__ float4 gather_row(const uint2* __restrict__ yb,
                                             const int* __restrict__ cp, int d, int ql) {
    float4 acc = make_float4(0.f, 0.f, 0.f, 0.f);
    for (int t = 0; t < d; t += 8) {
        int lim = d - 1 - t;
        int j1 = min(1, lim), j2 = min(2, lim), j3 = min(3, lim);
        int j4 = min(4, lim), j5 = min(5, lim), j6 = min(6, lim), j7 = min(7, lim);
        float m1 = lim >= 1 ? 1.f : 0.f, m2 = lim >= 2 ? 1.f : 0.f;
        float m3 = lim >= 3 ? 1.f : 0.f, m4 = lim >= 4 ? 1.f : 0.f;
        float m5 = lim >= 5 ? 1.f : 0.f, m6 = lim >= 6 ? 1.f : 0.f;
        float m7 = lim >= 7 ? 1.f : 0.f;
        int s0 = cp[t];
        int s1 = cp[t + j1];
        int s2 = cp[t + j2];
        int s3 = cp[t + j3];
        int s4 = cp[t + j4];
        int s5 = cp[t + j5];
        int s6 = cp[t + j6];
        int s7 = cp[t + j7];
        uint2 p0 = yb[(size_t)s0 * 16 + ql];
        uint2 p1 = yb[(size_t)s1 * 16 + ql];
        uint2 p2 = yb[(size_t)s2 * 16 + ql];
        uint2 p3 = yb[(size_t)s3 * 16 + ql];
        uint2 p4 = yb[(size_t)s4 * 16 + ql];
        uint2 p5 = yb[(size_t)s5 * 16 + ql];
        uint2 p6 = yb[(size_t)s6 * 16 + ql];
        uint2 p7 = yb[(size_t)s7 * 16 + ql];
        float4 v0 = bf4_to_f4(p0);
        float4 v1 = bf4_to_f4(p1);
        float4 v2 = bf4_to_f4(p2);
        float4 v3 = bf4_to_f4(p3);
        float4 v4 = bf4_to_f4(p4);
        float4 v5 = bf4_to_f4(p5);
        float4 v6 = bf4_to_f4(p6);
        float4 v7 = bf4_to_f4(p7);
        acc.x += v0.x;      acc.y += v0.y;      acc.z += v0.z;      acc.w += v0.w;
        acc.x += v1.x * m1; acc.y += v1.y * m1; acc.z += v1.z * m1; acc.w += v1.w * m1;
        acc.x += v2.x * m2; acc.y += v2.y * m2; acc.z += v2.z * m2; acc.w += v2.w * m2;
        acc.x += v3.x * m3; acc.y += v3.y * m3; acc.z += v3.z * m3; acc.w += v3.w * m3;
        acc.x += v4.x * m4; acc.y += v4.y * m4; acc.z += v4.z * m4; acc.w += v4.w * m4;
        acc.x += v5.x * m5; acc.y += v5.y * m5; acc.z += v5.z * m5; acc.w += v5.w * m5;
        acc.x += v6.x * m6; acc.y += v6.y * m6; acc.z += v6.z * m6; acc.w += v6.w * m6;
        acc.x += v7.x * m7; acc.y += v7.y * m7; acc.z += v7.z * m7; acc.w += v7.w * m7;
    }
    return acc;
}

// ---------------- fused: gather layer l -> prelu -> bf16 LDS -> MFMA transform l+1 ----------------
__global__ __launch_bounds__(512) void fused_gt_kernel(
    const uint2* __restrict__ yb, const float4* __restrict__ z4,
    const int* __restrict__ row_start, const int* __restrict__ deg,
    const float* __restrict__ deg_inv, const float* __restrict__ alpha,
    const int* __restrict__ csr_src,
    const float* __restrict__ Wl2, const float* __restrict__ Wr2,
    const float* __restrict__ bias2,
    unsigned short* __restrict__ yout, float* __restrict__ zout)
{
    __shared__ unsigned short wlT[64][72];
    __shared__ unsigned short wrT[64][72];
    __shared__ unsigned short xsb[32][72];
    __shared__ unsigned short ys[32][64];
    __shared__ float zs[32][64];
    __shared__ float bs2[C];

    int tid = threadIdx.x;
    for (int i = tid; i < C * C; i += 512) {
        int k = i >> 6, c = i & 63;
        wlT[c][k] = f2bf(Wl2[i]);
        wrT[c][k] = f2bf(Wr2[i]);
    }
    if (tid < C) bs2[tid] = bias2[tid];

    int nl = tid >> 4;
    int ql = tid & 15;
    int n = blockIdx.x * 32 + nl;

    float4 o = make_float4(0.f, 0.f, 0.f, 0.f);
    if (n < NN) {
        int rs = row_start[n];
        int d = deg[n];
        float4 acc = gather_row(yb, csr_src + rs, d, ql);
        float di = deg_inv[n];
        float4 zz = z4[(size_t)n * 16 + ql];
        float4 a4 = ((const float4*)alpha)[ql];
        o.x = di * acc.x + zz.x;
        o.y = di * acc.y + zz.y;
        o.z = di * acc.z + zz.z;
        o.w = di * acc.w + zz.w;
        o.x = o.x >= 0.f ? o.x : a4.x * o.x;
        o.y = o.y >= 0.f ? o.y : a4.y * o.y;
        o.z = o.z >= 0.f ? o.z : a4.z * o.z;
        o.w = o.w >= 0.f ? o.w : a4.w * o.w;
    }
    {
        ushort4 p = make_ushort4(f2bf(o.x), f2bf(o.y), f2bf(o.z), f2bf(o.w));
        *(ushort4*)&xsb[nl][ql * 4] = p;
    }
    __syncthreads();

    int w = tid >> 6;
    int l = tid & 63;
    int mt = w & 1;
    int half = (w >> 1) & 1;
    int ntg = w >> 2;
    int r16 = l & 15;
    int kg = l >> 4;

    bf16x8 a0 = *(const bf16x8*)&xsb[mt * 16 + r16][kg * 8];
    bf16x8 a1 = *(const bf16x8*)&xsb[mt * 16 + r16][32 + kg * 8];

    #pragma unroll
    for (int q = 0; q < 2; q++) {
        int nt = ntg * 2 + q;
        const unsigned short* col = half ? &wrT[nt * 16 + r16][0] : &wlT[nt * 16 + r16][0];
        bf16x8 b0 = *(const bf16x8*)&col[kg * 8];
        bf16x8 b1 = *(const bf16x8*)&col[32 + kg * 8];
        float bv = half ? bs2[nt * 16 + r16] : 0.f;
        f32x4 acc = (f32x4){bv, bv, bv, bv};
        acc = __builtin_amdgcn_mfma_f32_16x16x32_bf16(a0, b0, acc, 0, 0, 0);
        acc = __builtin_amdgcn_mfma_f32_16x16x32_bf16(a1, b1, acc, 0, 0, 0);
        #pragma unroll
        for (int j = 0; j < 4; j++) {
            int r = mt * 16 + kg * 4 + j;
            int c = nt * 16 + r16;
            if (half) zs[r][c] = acc[j];
            else      ys[r][c] = f2bf(acc[j]);
        }
    }
    __syncthreads();

    {
        int r = tid >> 4, g = tid & 15;
        int n2 = blockIdx.x * 32 + r;
        if (n2 < NN) {
            ((ushort4*)&yout[(size_t)n2 * C])[g] = ((const ushort4*)&ys[r][0])[g];
            ((float4*)&zout[(size_t)n2 * C])[g] = ((const float4*)&zs[r][0])[g];
        }
    }
}

// ---------------- final gather (layer 3): writes d_out fp32 ----------------
__global__ __launch_bounds__(256) void gather_kernel(
    const uint2* __restrict__ yb, const float4* __restrict__ z4,
    const int* __restrict__ row_start, const int* __restrict__ deg,
    const float* __restrict__ deg_inv, const float* __restrict__ alpha,
    const int* __restrict__ csr_src,
    float4* __restrict__ out4)
{
    int tid = threadIdx.x;
    int n = blockIdx.x * 16 + (tid >> 4);
    int ql = tid & 15;

    int rs = row_start[n];
    int d = deg[n];
    float4 acc = gather_row(yb, csr_src + rs, d, ql);

    float di = deg_inv[n];
    float4 zz = z4[(size_t)n * 16 + ql];
    float4 a4 = ((const float4*)alpha)[ql];
    float4 o;
    o.x = di * acc.x + zz.x;
    o.y = di * acc.y + zz.y;
    o.z = di * acc.z + zz.z;
    o.w = di * acc.w + zz.w;
    o.x = o.x >= 0.f ? o.x : a4.x * o.x;
    o.y = o.y >= 0.f ? o.y : a4.y * o.y;
    o.z = o.z >= 0.f ? o.z : a4.z * o.z;
    o.w = o.w >= 0.f ? o.w : a4.w * o.w;
    out4[(size_t)n * 16 + ql] = o;
}

extern "C" void kernel_launch(void* const* d_in, const int* in_sizes, int n_in,
                              void* d_out, int out_size, void* d_ws, size_t ws_size,
                              hipStream_t stream) {
    const float* x     = (const float*)d_in[0];
    const int*   ei    = (const int*)d_in[1];
    const float* Wl    = (const float*)d_in[2];
    const float* Wr    = (const float*)d_in[3];
    const float* b     = (const float*)d_in[4];
    const float* alpha = (const float*)d_in[5];
    float* out = (float*)d_out;

    const int* src = ei;        // edge_index[0]
    const int* dst = ei + NE;   // edge_index[1]

    // workspace layout (all 16B-aligned; everything fully rewritten each call)
    char* wsp = (char*)d_ws;
    int*  lrank        = (int*)wsp;                 wsp += (size_t)NE * 4;        // aliased by csr_src
    int*  blk_cnt      = (int*)wsp;                 wsp += (size_t)NBK * HBLK * 4 + 256;
    int*  bucket_tot   = (int*)wsp;                 wsp += 1024;
    int2* sorted       = (int2*)wsp;                wsp += (size_t)NE * 8;
    int*  deg          = (int*)wsp;                 wsp += (size_t)(NBK * 256) * 4;
    float* deg_inv     = (float*)wsp;               wsp += (size_t)NN * 4;
    int*  row_start    = (int*)wsp;                 wsp += (size_t)NN * 4;
    unsigned short* y0buf = (unsigned short*)wsp;   wsp += (size_t)NN * C * 2;
    unsigned short* y1buf = (unsigned short*)wsp;   wsp += (size_t)NN * C * 2;
    float* z0buf       = (float*)wsp;               wsp += (size_t)NN * C * 4;
    float* z1buf       = (float*)wsp;
    int*  csr_src      = lrank;   // lrank dead after bucket_scatter; csr written after

    // ---- CSR build: bucket-sorted, LDS-atomic only, 4 kernels ----
    bucket_hist_kernel<<<HBLK, 1024, 0, stream>>>(dst, blk_cnt, lrank);
    scanblk_kernel<<<NBK, 1024, 0, stream>>>(blk_cnt, bucket_tot);
    bucket_scatter_kernel<<<HBLK, 1024, 0, stream>>>(src, dst, lrank, blk_cnt,
                                                     bucket_tot, sorted);
    bucket_finalize_kernel<<<NBK, 512, 0, stream>>>(sorted, bucket_tot,
                                                    row_start, deg, deg_inv, csr_src);

    // ---- layer-0 transform (MFMA) ----
    transform_mfma_kernel<<<(NN + 63) / 64, 512, 0, stream>>>(x, Wl, Wr, b, y0buf, z0buf);

    // ---- fused (gather_l + MFMA transform_{l+1}) for l = 0,1,2; ping-pong ----
    const int fblocks = (NN + 31) / 32;
    unsigned short* ycur = y0buf; float* zcur = z0buf;
    unsigned short* ynxt = y1buf; float* znxt = z1buf;
    for (int l = 0; l < NL - 1; l++) {
        fused_gt_kernel<<<fblocks, 512, 0, stream>>>(
            (const uint2*)ycur, (const float4*)zcur,
            row_start, deg, deg_inv, alpha + (size_t)l * C, csr_src,
            Wl + (size_t)(l + 1) * C * C, Wr + (size_t)(l + 1) * C * C,
            b + (size_t)(l + 1) * C,
            ynxt, znxt);
        unsigned short* ty = ycur; float* tz = zcur;
        ycur = ynxt; zcur = znxt;
        ynxt = ty;   znxt = tz;
    }

    // ---- final gather (layer 3) -> d_out ----
    gather_kernel<<<NN / 16, 256, 0, stream>>>(
        (const uint2*)ycur, (const float4*)zcur, row_start, deg,
        deg_inv, alpha + (size_t)(NL - 1) * C, csr_src, (float4*)out);
}